// Round 2
// baseline (2427.263 us; speedup 1.0000x reference)
//
#include <hip/hip_runtime.h>

#define H_ 256
#define M_ 256
#define L_ 4096
#define B_ 16
#define PI_F 3.14159265358979323846f

__device__ __forceinline__ float sigm(float x) { return 1.0f / (1.0f + expf(-x)); }

// ---------------- prep: de-interleave weights, per-m constants ----------------
__global__ __launch_bounds__(256) void k_prep(const float* __restrict__ Bp,   // (M,H,2)
                                              const float* __restrict__ Cp,   // (H,M,2)
                                              const float* __restrict__ dtb,  // (M,)
                                              float* __restrict__ Bre, float* __restrict__ Bim,
                                              float* __restrict__ Chat,       // (H,2M): [h][2m]=Cre, [h][2m+1]=-Cim
                                              float* __restrict__ dtc, float* __restrict__ idt,
                                              float* __restrict__ idt2) {
    int tid = blockIdx.x * 256 + threadIdx.x;  // 0..65535
    if (tid < M_) {
        float d = fmaxf(sigm(dtb[tid]), 1e-6f);
        dtc[tid] = d;
        idt[tid] = 1.0f / d;
        idt2[tid] = 1.0f / (d * d);
    }
    Bre[tid] = Bp[2 * tid + 0];
    Bim[tid] = Bp[2 * tid + 1];
    int h = tid >> 8, m = tid & (M_ - 1);
    Chat[h * (2 * M_) + 2 * m + 0] = Cp[2 * tid + 0];
    Chat[h * (2 * M_) + 2 * m + 1] = -Cp[2 * tid + 1];
}

__global__ __launch_bounds__(256) void k_zero(float* __restrict__ p, int n) {
    int i = blockIdx.x * 256 + threadIdx.x;
    if (i < n) p[i] = 0.0f;
}

// ---------------- encoder GEMM + SiLU (chunked, with 64-row halo) ----------------
__global__ __launch_bounds__(256) void k_enc(const float* __restrict__ X,  // (B*L,H) global
                                             const float* __restrict__ W,  // (H,H)
                                             const float* __restrict__ bias,
                                             float* __restrict__ Y,        // (B*(C+64),H) local
                                             int t0, int C, int tpb) {    // tpb = C/64+1
    __shared__ float As[16][68];
    __shared__ float Bs[16][68];
    const int tid = threadIdx.x;
    const int tx = tid & 15, ty = tid >> 4;
    const int tileY = blockIdx.y;
    const int batch = tileY / tpb;
    const int tw = tileY - batch * tpb;
    const int lrowBase = batch * (C + 64) + (tw << 6);
    const int colBase = blockIdx.x << 6;
    const int lr = tid >> 2;
    const int lc = (tid & 3) << 2;
    int t_row = t0 - 64 + (tw << 6) + lr;
    t_row = min(max(t_row, 0), L_ - 1);
    const size_t growA = (size_t)(batch * L_ + t_row) * H_;
    float acc[4][4] = {};
    for (int k0 = 0; k0 < H_; k0 += 16) {
        float4 xa = *(const float4*)&X[growA + k0 + lc];
        float4 wb = *(const float4*)&W[(size_t)(colBase + lr) * H_ + k0 + lc];
        As[lc + 0][lr] = xa.x; As[lc + 1][lr] = xa.y; As[lc + 2][lr] = xa.z; As[lc + 3][lr] = xa.w;
        Bs[lc + 0][lr] = wb.x; Bs[lc + 1][lr] = wb.y; Bs[lc + 2][lr] = wb.z; Bs[lc + 3][lr] = wb.w;
        __syncthreads();
#pragma unroll
        for (int kk = 0; kk < 16; ++kk) {
            float4 a = *(const float4*)&As[kk][ty << 2];
            float4 b = *(const float4*)&Bs[kk][tx << 2];
            float av[4] = {a.x, a.y, a.z, a.w}, bv[4] = {b.x, b.y, b.z, b.w};
#pragma unroll
            for (int i = 0; i < 4; ++i)
#pragma unroll
                for (int j = 0; j < 4; ++j) acc[i][j] = fmaf(av[i], bv[j], acc[i][j]);
        }
        __syncthreads();
    }
#pragma unroll
    for (int i = 0; i < 4; ++i) {
        int row = lrowBase + (ty << 2) + i;
        int col0 = colBase + (tx << 2);
        float v0 = acc[i][0] + bias[col0 + 0];
        float v1 = acc[i][1] + bias[col0 + 1];
        float v2 = acc[i][2] + bias[col0 + 2];
        float v3 = acc[i][3] + bias[col0 + 3];
        float4 o;
        o.x = v0 * sigm(v0); o.y = v1 * sigm(v1); o.z = v2 * sigm(v2); o.w = v3 * sigm(v3);
        *(float4*)&Y[(size_t)row * H_ + col0] = o;
    }
}

// ---------------- depthwise causal conv (K=4) + SiLU (chunked) ----------------
__global__ __launch_bounds__(256) void k_conv(const float* __restrict__ F0,  // (B*(C+64),H)
                                              const float* __restrict__ cw,  // (H,1,4)
                                              const float* __restrict__ cb,
                                              float* __restrict__ F,         // (B*C,H)
                                              int t0, int C) {
    int idx = blockIdx.x * 256 + threadIdx.x;  // over B*C*H
    int h = idx & (H_ - 1);
    int rl = idx >> 8;           // local row: b*C + dtl
    int b = rl / C;
    int dtl = rl - b * C;
    int t = t0 + dtl;            // global time
    size_t base = (size_t)(b * (C + 64) + dtl + 64) * H_ + h;
    float w0 = cw[h * 4 + 0], w1 = cw[h * 4 + 1], w2 = cw[h * 4 + 2], w3 = cw[h * 4 + 3];
    float acc = cb[h];
    acc = fmaf(F0[base], w3, acc);
    if (t >= 1) acc = fmaf(F0[base - H_], w2, acc);
    if (t >= 2) acc = fmaf(F0[base - 2 * H_], w1, acc);
    if (t >= 3) acc = fmaf(F0[base - 3 * H_], w0, acc);
    F[(size_t)rl * H_ + h] = acc * sigm(acc);
}

// ---------------- heads: r/theta/gate GEMMs (local rows) ----------------
__global__ __launch_bounds__(256) void k_heads(const float* __restrict__ F,   // (B*C,H)
                                               const float* __restrict__ Wr,
                                               const float* __restrict__ Wt,
                                               const float* __restrict__ Wg,
                                               const float* __restrict__ rlb,
                                               const float* __restrict__ tab,
                                               const float* __restrict__ idt,
                                               const float* __restrict__ idt2,
                                               float* __restrict__ AG) {      // (B*C,M) float4
    __shared__ float As[16][68];
    __shared__ float Br[16][68], Bt[16][68], Bg[16][68];
    const int tid = threadIdx.x;
    const int tx = tid & 15, ty = tid >> 4;
    const int rowBase = blockIdx.y << 6;
    const int colBase = blockIdx.x << 6;
    const int lr = tid >> 2;
    const int lc = (tid & 3) << 2;
    float accR[4][4] = {}, accT[4][4] = {}, accG[4][4] = {};
    for (int k0 = 0; k0 < H_; k0 += 16) {
        float4 xa = *(const float4*)&F[(size_t)(rowBase + lr) * H_ + k0 + lc];
        float4 wr = *(const float4*)&Wr[(size_t)(colBase + lr) * H_ + k0 + lc];
        float4 wt = *(const float4*)&Wt[(size_t)(colBase + lr) * H_ + k0 + lc];
        float4 wg = *(const float4*)&Wg[(size_t)(colBase + lr) * H_ + k0 + lc];
        As[lc + 0][lr] = xa.x; As[lc + 1][lr] = xa.y; As[lc + 2][lr] = xa.z; As[lc + 3][lr] = xa.w;
        Br[lc + 0][lr] = wr.x; Br[lc + 1][lr] = wr.y; Br[lc + 2][lr] = wr.z; Br[lc + 3][lr] = wr.w;
        Bt[lc + 0][lr] = wt.x; Bt[lc + 1][lr] = wt.y; Bt[lc + 2][lr] = wt.z; Bt[lc + 3][lr] = wt.w;
        Bg[lc + 0][lr] = wg.x; Bg[lc + 1][lr] = wg.y; Bg[lc + 2][lr] = wg.z; Bg[lc + 3][lr] = wg.w;
        __syncthreads();
#pragma unroll
        for (int kk = 0; kk < 16; ++kk) {
            float4 a = *(const float4*)&As[kk][ty << 2];
            float av[4] = {a.x, a.y, a.z, a.w};
            float4 br = *(const float4*)&Br[kk][tx << 2];
            float4 bt = *(const float4*)&Bt[kk][tx << 2];
            float4 bg = *(const float4*)&Bg[kk][tx << 2];
            float brv[4] = {br.x, br.y, br.z, br.w};
            float btv[4] = {bt.x, bt.y, bt.z, bt.w};
            float bgv[4] = {bg.x, bg.y, bg.z, bg.w};
#pragma unroll
            for (int i = 0; i < 4; ++i)
#pragma unroll
                for (int j = 0; j < 4; ++j) {
                    accR[i][j] = fmaf(av[i], brv[j], accR[i][j]);
                    accT[i][j] = fmaf(av[i], btv[j], accT[i][j]);
                    accG[i][j] = fmaf(av[i], bgv[j], accG[i][j]);
                }
        }
        __syncthreads();
    }
#pragma unroll
    for (int i = 0; i < 4; ++i) {
        int row = rowBase + (ty << 2) + i;
#pragma unroll
        for (int j = 0; j < 4; ++j) {
            int col = colBase + (tx << 2) + j;
            float r = sigm(rlb[col] + accR[i][j]);
            float th = PI_F * tanhf(tab[col] + accT[i][j]);
            float r2 = fmaxf(r * r, 1e-8f);
            float A = fmaxf((r2 - 2.0f * r * cosf(th) + 1.0f) * idt2[col] / r2, 0.0f);
            float G = fmaxf((1.0f - r2) * idt[col] / r2, 0.0f);
            float g = sigm(accG[i][j]);
            float4 o; o.x = A; o.y = G; o.z = g; o.w = 0.0f;
            *(float4*)&AG[((size_t)row * M_ + col) * 4] = o;
        }
    }
}

// ---------------- bu GEMMs from inputs (global rows), gated, into AG.zw ----------------
__global__ __launch_bounds__(256) void k_bu(const float* __restrict__ X,
                                            const float* __restrict__ WBre,
                                            const float* __restrict__ WBim,
                                            float* __restrict__ AG,
                                            int t0, int C, int tpb2) {  // tpb2 = C/64
    __shared__ float As[16][68];
    __shared__ float Br[16][68], Bi[16][68];
    const int tid = threadIdx.x;
    const int tx = tid & 15, ty = tid >> 4;
    const int tileY = blockIdx.y;
    const int batch = tileY / tpb2;
    const int tw = tileY - batch * tpb2;
    const int growBase = batch * L_ + t0 + (tw << 6);  // global rows for X
    const int lrowBase = batch * C + (tw << 6);        // local rows for AG
    const int colBase = blockIdx.x << 6;
    const int lr = tid >> 2;
    const int lc = (tid & 3) << 2;
    float accR[4][4] = {}, accI[4][4] = {};
    for (int k0 = 0; k0 < H_; k0 += 16) {
        float4 xa = *(const float4*)&X[(size_t)(growBase + lr) * H_ + k0 + lc];
        float4 wr = *(const float4*)&WBre[(size_t)(colBase + lr) * H_ + k0 + lc];
        float4 wi = *(const float4*)&WBim[(size_t)(colBase + lr) * H_ + k0 + lc];
        As[lc + 0][lr] = xa.x; As[lc + 1][lr] = xa.y; As[lc + 2][lr] = xa.z; As[lc + 3][lr] = xa.w;
        Br[lc + 0][lr] = wr.x; Br[lc + 1][lr] = wr.y; Br[lc + 2][lr] = wr.z; Br[lc + 3][lr] = wr.w;
        Bi[lc + 0][lr] = wi.x; Bi[lc + 1][lr] = wi.y; Bi[lc + 2][lr] = wi.z; Bi[lc + 3][lr] = wi.w;
        __syncthreads();
#pragma unroll
        for (int kk = 0; kk < 16; ++kk) {
            float4 a = *(const float4*)&As[kk][ty << 2];
            float av[4] = {a.x, a.y, a.z, a.w};
            float4 br = *(const float4*)&Br[kk][tx << 2];
            float4 bi = *(const float4*)&Bi[kk][tx << 2];
            float brv[4] = {br.x, br.y, br.z, br.w};
            float biv[4] = {bi.x, bi.y, bi.z, bi.w};
#pragma unroll
            for (int i = 0; i < 4; ++i)
#pragma unroll
                for (int j = 0; j < 4; ++j) {
                    accR[i][j] = fmaf(av[i], brv[j], accR[i][j]);
                    accI[i][j] = fmaf(av[i], biv[j], accI[i][j]);
                }
        }
        __syncthreads();
    }
#pragma unroll
    for (int i = 0; i < 4; ++i) {
        int row = lrowBase + (ty << 2) + i;
#pragma unroll
        for (int j = 0; j < 4; ++j) {
            int col = colBase + (tx << 2) + j;
            size_t base = ((size_t)row * M_ + col) * 4;
            float gate = AG[base + 2];
            float2 o; o.x = accR[i][j] * gate; o.y = accI[i][j] * gate;
            *(float2*)&AG[base + 2] = o;
        }
    }
}

// ---------------- sequential scan over chunk, carry in global ----------------
__global__ __launch_bounds__(64) void k_scan(const float* __restrict__ AG,
                                             const float* __restrict__ dtc_,
                                             float* __restrict__ carry,  // (B*M) float4: zr,zi,xr,xi
                                             float* __restrict__ XS,     // (B*C, 2M)
                                             int C) {
    int lane = threadIdx.x;
    int b = blockIdx.x >> 2;
    int m = ((blockIdx.x & 3) << 6) + lane;
    float dt = dtc_[m];
    float4 cz = *(float4*)&carry[(size_t)(b * M_ + m) * 4];
    float zr = cz.x, zi = cz.y, xr = cz.z, xi = cz.w;
    const float4* p = (const float4*)AG + (size_t)b * C * M_ + m;
    float2* q = (float2*)XS + (size_t)b * C * M_ + m;
    for (int t = 0; t < C; ++t) {
        float4 v = p[(size_t)t * M_];
        float S = fmaf(dt, v.y, 1.0f);
        float inv = 1.0f / fmaxf(S, 1e-6f);
        zr = fmaf(dt, fmaf(-v.x, xr, v.z), zr) * inv;
        zi = fmaf(dt, fmaf(-v.x, xi, v.w), zi) * inv;
        xr = fmaf(dt, zr, xr);
        xi = fmaf(dt, zi, xi);
        q[(size_t)t * M_] = make_float2(xr, xi);
    }
    *(float4*)&carry[(size_t)(b * M_ + m) * 4] = make_float4(zr, zi, xr, xi);
}

// ---------------- projection GEMM (K=512) + D*x residual ----------------
__global__ __launch_bounds__(256) void k_proj(const float* __restrict__ XS,   // (B*C,512)
                                              const float* __restrict__ Chat, // (H,512)
                                              const float* __restrict__ Dv,
                                              const float* __restrict__ X0,   // global
                                              float* __restrict__ OUT,        // global
                                              int t0, int C, int tpb2) {
    __shared__ float As[16][68];
    __shared__ float Bs[16][68];
    const int tid = threadIdx.x;
    const int tx = tid & 15, ty = tid >> 4;
    const int tileY = blockIdx.y;
    const int batch = tileY / tpb2;
    const int tw = tileY - batch * tpb2;
    const int lrowBase = batch * C + (tw << 6);
    const int growBase = batch * L_ + t0 + (tw << 6);
    const int colBase = blockIdx.x << 6;
    const int lr = tid >> 2;
    const int lc = (tid & 3) << 2;
    const int KT = 2 * M_;
    float acc[4][4] = {};
    for (int k0 = 0; k0 < KT; k0 += 16) {
        float4 xa = *(const float4*)&XS[(size_t)(lrowBase + lr) * KT + k0 + lc];
        float4 wb = *(const float4*)&Chat[(size_t)(colBase + lr) * KT + k0 + lc];
        As[lc + 0][lr] = xa.x; As[lc + 1][lr] = xa.y; As[lc + 2][lr] = xa.z; As[lc + 3][lr] = xa.w;
        Bs[lc + 0][lr] = wb.x; Bs[lc + 1][lr] = wb.y; Bs[lc + 2][lr] = wb.z; Bs[lc + 3][lr] = wb.w;
        __syncthreads();
#pragma unroll
        for (int kk = 0; kk < 16; ++kk) {
            float4 a = *(const float4*)&As[kk][ty << 2];
            float4 b = *(const float4*)&Bs[kk][tx << 2];
            float av[4] = {a.x, a.y, a.z, a.w}, bv[4] = {b.x, b.y, b.z, b.w};
#pragma unroll
            for (int i = 0; i < 4; ++i)
#pragma unroll
                for (int j = 0; j < 4; ++j) acc[i][j] = fmaf(av[i], bv[j], acc[i][j]);
        }
        __syncthreads();
    }
#pragma unroll
    for (int i = 0; i < 4; ++i) {
        int grow = growBase + (ty << 2) + i;
        int col0 = colBase + (tx << 2);
        float4 x0 = *(const float4*)&X0[(size_t)grow * H_ + col0];
        float4 o;
        o.x = acc[i][0] + Dv[col0 + 0] * x0.x;
        o.y = acc[i][1] + Dv[col0 + 1] * x0.y;
        o.z = acc[i][2] + Dv[col0 + 2] * x0.z;
        o.w = acc[i][3] + Dv[col0 + 3] * x0.w;
        *(float4*)&OUT[(size_t)grow * H_ + col0] = o;
    }
}

extern "C" void kernel_launch(void* const* d_in, const int* in_sizes, int n_in,
                              void* d_out, int out_size, void* d_ws, size_t ws_size,
                              hipStream_t stream) {
    const float* inputs = (const float*)d_in[0];
    const float* Bp     = (const float*)d_in[1];
    const float* Cp     = (const float*)d_in[2];
    const float* Dv     = (const float*)d_in[3];
    const float* enc_w  = (const float*)d_in[4];
    const float* enc_b  = (const float*)d_in[5];
    const float* conv_w = (const float*)d_in[6];
    const float* conv_b = (const float*)d_in[7];
    const float* rlb    = (const float*)d_in[8];
    const float* tab    = (const float*)d_in[9];
    const float* Wr     = (const float*)d_in[10];
    const float* Wt     = (const float*)d_in[11];
    const float* dtb    = (const float*)d_in[12];
    const float* Wg     = (const float*)d_in[13];

    // pick largest chunk length C that fits ws_size
    int C = 4096;
    while (C > 64) {
        size_t need = (size_t)B_ * (C + 64) * H_ * 4   // F0
                    + (size_t)B_ * C * H_ * 4          // F
                    + (size_t)B_ * C * M_ * 16         // AG
                    + (size_t)B_ * C * 2 * M_ * 4      // XS
                    + (4ull << 20);                    // tables + slack
        if (need <= ws_size) break;
        C >>= 1;
    }

    char* ws = (char*)d_ws;
    size_t off = 0;
    auto alloc = [&](size_t bytes) -> float* {
        float* p = (float*)(ws + off);
        off = (off + bytes + 1023) & ~(size_t)1023;
        return p;
    };
    float* F0   = alloc((size_t)B_ * (C + 64) * H_ * 4);
    float* F    = alloc((size_t)B_ * C * H_ * 4);
    float* AG   = alloc((size_t)B_ * C * M_ * 16);
    float* XS   = alloc((size_t)B_ * C * 2 * M_ * 4);
    float* Bre  = alloc(M_ * H_ * 4);
    float* Bim  = alloc(M_ * H_ * 4);
    float* Chat = alloc(H_ * 2 * M_ * 4);
    float* dtc  = alloc(1024);
    float* idt  = alloc(1024);
    float* idt2 = alloc(1024);
    float* carry = alloc(B_ * M_ * 16);

    const int tpb = C / 64 + 1;   // enc tiles per batch (with halo)
    const int tpb2 = C / 64;      // plain tiles per batch
    const int NC = L_ / C;

    k_prep<<<256, 256, 0, stream>>>(Bp, Cp, dtb, Bre, Bim, Chat, dtc, idt, idt2);
    k_zero<<<(B_ * M_ * 4 + 255) / 256, 256, 0, stream>>>(carry, B_ * M_ * 4);

    for (int c = 0; c < NC; ++c) {
        int t0 = c * C;
        k_enc<<<dim3(4, B_ * tpb), 256, 0, stream>>>(inputs, enc_w, enc_b, F0, t0, C, tpb);
        k_conv<<<B_ * C, 256, 0, stream>>>(F0, conv_w, conv_b, F, t0, C);
        k_heads<<<dim3(4, B_ * tpb2), 256, 0, stream>>>(F, Wr, Wt, Wg, rlb, tab, idt, idt2, AG);
        k_bu<<<dim3(4, B_ * tpb2), 256, 0, stream>>>(inputs, Bre, Bim, AG, t0, C, tpb2);
        k_scan<<<64, 64, 0, stream>>>(AG, dtc, carry, XS, C);
        k_proj<<<dim3(4, B_ * tpb2), 256, 0, stream>>>(XS, Chat, Dv, inputs, (float*)d_out, t0, C, tpb2);
    }
}

// Round 3
// 1332.656 us; speedup vs baseline: 1.8214x; 1.8214x over previous
//
#include <hip/hip_runtime.h>

#define H_ 256
#define M_ 256
#define L_ 4096
#define B_ 16
#define PI_F 3.14159265358979323846f

__device__ __forceinline__ float sigm(float x) { return 1.0f / (1.0f + expf(-x)); }

// ---------------- prep: pack weights, per-m constants ----------------
__global__ __launch_bounds__(256) void k_prep(const float* __restrict__ Bp,   // (M,H,2)
                                              const float* __restrict__ Cp,   // (H,M,2)
                                              const float* __restrict__ Wr,
                                              const float* __restrict__ Wt,
                                              const float* __restrict__ Wg,
                                              const float* __restrict__ dtb,
                                              float* __restrict__ WB,    // (512,256): Bre rows, Bim rows
                                              float* __restrict__ WH,    // (768,256): Wr, Wt, Wg
                                              float* __restrict__ Chat,  // (H,512): [h][2m]=Cre,[h][2m+1]=-Cim
                                              float* __restrict__ dtc, float* __restrict__ idt,
                                              float* __restrict__ idt2) {
    int tid = blockIdx.x * 256 + threadIdx.x;  // 0..65535
    if (tid < M_) {
        float d = fmaxf(sigm(dtb[tid]), 1e-6f);
        dtc[tid] = d;
        idt[tid] = 1.0f / d;
        idt2[tid] = 1.0f / (d * d);
    }
    WB[tid]         = Bp[2 * tid + 0];
    WB[65536 + tid] = Bp[2 * tid + 1];
    WH[tid]          = Wr[tid];
    WH[65536 + tid]  = Wt[tid];
    WH[131072 + tid] = Wg[tid];
    int h = tid >> 8, m = tid & (M_ - 1);
    Chat[h * 512 + 2 * m + 0] = Cp[2 * tid + 0];
    Chat[h * 512 + 2 * m + 1] = -Cp[2 * tid + 1];
}

__global__ __launch_bounds__(256) void k_zero(float* __restrict__ p, int n) {
    int i = blockIdx.x * 256 + threadIdx.x;
    if (i < n) p[i] = 0.0f;
}

// ---------------- generic fp32 GEMM: OUT(rows,N) = A(rows,K) @ W(N,K)^T ----------------
// 128x128 tile, 8x8 micro (split +-64), 256 threads.
// EPI: 0=raw, 1=silu(acc+bias), 2=acc + aux1[col]*aux2[globalrow][col]
template <int EPI, bool AGLOB, bool OGLOB>
__global__ __launch_bounds__(256) void k_gemm(const float* __restrict__ A,
                                              const float* __restrict__ W,
                                              float* __restrict__ OUT,
                                              const float* __restrict__ aux1,
                                              const float* __restrict__ aux2,
                                              int K, int N, int C, int t0) {
    __shared__ float As[16][132];
    __shared__ float Bs[16][132];
    const int tid = threadIdx.x;
    const int tx = tid & 15, ty = tid >> 4;
    const int tpb = C >> 7;
    const int batch = blockIdx.y / tpb;
    const int i0 = (blockIdx.y % tpb) << 7;
    const int aRow0 = AGLOB ? (batch * L_ + t0 + i0) : (batch * C + i0);
    const int oRow0 = OGLOB ? (batch * L_ + t0 + i0) : (batch * C + i0);
    const int colBase = blockIdx.x << 7;
    const int lr = tid >> 2;        // 0..63
    const int lk = (tid & 3) << 2;  // 0,4,8,12
    float acc[8][8] = {};
    for (int k0 = 0; k0 < K; k0 += 16) {
        float4 a0 = *(const float4*)&A[(size_t)(aRow0 + lr) * K + k0 + lk];
        float4 a1 = *(const float4*)&A[(size_t)(aRow0 + 64 + lr) * K + k0 + lk];
        float4 b0 = *(const float4*)&W[(size_t)(colBase + lr) * K + k0 + lk];
        float4 b1 = *(const float4*)&W[(size_t)(colBase + 64 + lr) * K + k0 + lk];
        __syncthreads();
        As[lk + 0][lr] = a0.x; As[lk + 1][lr] = a0.y; As[lk + 2][lr] = a0.z; As[lk + 3][lr] = a0.w;
        As[lk + 0][64 + lr] = a1.x; As[lk + 1][64 + lr] = a1.y; As[lk + 2][64 + lr] = a1.z; As[lk + 3][64 + lr] = a1.w;
        Bs[lk + 0][lr] = b0.x; Bs[lk + 1][lr] = b0.y; Bs[lk + 2][lr] = b0.z; Bs[lk + 3][lr] = b0.w;
        Bs[lk + 0][64 + lr] = b1.x; Bs[lk + 1][64 + lr] = b1.y; Bs[lk + 2][64 + lr] = b1.z; Bs[lk + 3][64 + lr] = b1.w;
        __syncthreads();
#pragma unroll
        for (int kk = 0; kk < 16; ++kk) {
            float4 av0 = *(const float4*)&As[kk][ty << 2];
            float4 av1 = *(const float4*)&As[kk][64 + (ty << 2)];
            float4 bv0 = *(const float4*)&Bs[kk][tx << 2];
            float4 bv1 = *(const float4*)&Bs[kk][64 + (tx << 2)];
            float av[8] = {av0.x, av0.y, av0.z, av0.w, av1.x, av1.y, av1.z, av1.w};
            float bv[8] = {bv0.x, bv0.y, bv0.z, bv0.w, bv1.x, bv1.y, bv1.z, bv1.w};
#pragma unroll
            for (int i = 0; i < 8; ++i)
#pragma unroll
                for (int j = 0; j < 8; ++j) acc[i][j] = fmaf(av[i], bv[j], acc[i][j]);
        }
    }
#pragma unroll
    for (int ih = 0; ih < 2; ++ih)
#pragma unroll
        for (int i = 0; i < 4; ++i) {
            int orow = oRow0 + ih * 64 + (ty << 2) + i;
#pragma unroll
            for (int jh = 0; jh < 2; ++jh) {
                int col = colBase + jh * 64 + (tx << 2);
                float4 o;
                o.x = acc[ih * 4 + i][jh * 4 + 0];
                o.y = acc[ih * 4 + i][jh * 4 + 1];
                o.z = acc[ih * 4 + i][jh * 4 + 2];
                o.w = acc[ih * 4 + i][jh * 4 + 3];
                if (EPI == 1) {
                    float4 bb = *(const float4*)&aux1[col];
                    float v0 = o.x + bb.x, v1 = o.y + bb.y, v2 = o.z + bb.z, v3 = o.w + bb.w;
                    o.x = v0 * sigm(v0); o.y = v1 * sigm(v1); o.z = v2 * sigm(v2); o.w = v3 * sigm(v3);
                } else if (EPI == 2) {
                    float4 dd = *(const float4*)&aux1[col];
                    float4 x0 = *(const float4*)&aux2[(size_t)orow * H_ + col];
                    o.x = fmaf(dd.x, x0.x, o.x); o.y = fmaf(dd.y, x0.y, o.y);
                    o.z = fmaf(dd.z, x0.z, o.z); o.w = fmaf(dd.w, x0.w, o.w);
                }
                *(float4*)&OUT[(size_t)orow * N + col] = o;
            }
        }
}

// ---------------- depthwise causal conv (K=4) + SiLU ----------------
__global__ __launch_bounds__(256) void k_conv(const float* __restrict__ F0,   // (B*C,H)
                                              const float* __restrict__ TAIL, // (B,3,H) rows t0-3..t0-1
                                              const float* __restrict__ cw,
                                              const float* __restrict__ cb,
                                              float* __restrict__ F,
                                              int t0, int C) {
    int idx = blockIdx.x * 256 + threadIdx.x;
    int h = idx & (H_ - 1);
    int rl = idx >> 8;
    int b = rl / C;
    int dtl = rl - b * C;
    int t = t0 + dtl;
    float w0 = cw[h * 4 + 0], w1 = cw[h * 4 + 1], w2 = cw[h * 4 + 2], w3 = cw[h * 4 + 3];
    float acc = cb[h];
    acc = fmaf(F0[(size_t)rl * H_ + h], w3, acc);
#pragma unroll
    for (int kk = 1; kk <= 3; ++kk) {
        float w = (kk == 1) ? w2 : (kk == 2) ? w1 : w0;
        if (t - kk >= 0) {
            float src;
            if (dtl - kk >= 0) src = F0[(size_t)(rl - kk) * H_ + h];
            else               src = TAIL[((b * 3 + (3 + dtl - kk)) << 8) + h];
            acc = fmaf(src, w, acc);
        }
    }
    F[(size_t)rl * H_ + h] = acc * sigm(acc);
}

__global__ __launch_bounds__(256) void k_tail(const float* __restrict__ F0,
                                              float* __restrict__ TAIL, int C) {
    int b = blockIdx.x / 3, j = blockIdx.x % 3, h = threadIdx.x;
    TAIL[((b * 3 + j) << 8) + h] = F0[((size_t)(b * C + C - 3 + j) << 8) + h];
}

// ---------------- assemble A,G,gated-bu into AG float4 ----------------
__global__ __launch_bounds__(256) void k_assemble(const float* __restrict__ LOG,  // (rows,768)
                                                  const float* __restrict__ BU,   // (rows,512)
                                                  const float* __restrict__ rlb,
                                                  const float* __restrict__ tab,
                                                  const float* __restrict__ idt,
                                                  const float* __restrict__ idt2,
                                                  float* __restrict__ AG) {
    int row = blockIdx.x;
    int m = threadIdx.x;
    size_t lb = (size_t)row * 768;
    float r = sigm(rlb[m] + LOG[lb + m]);
    float th = PI_F * tanhf(tab[m] + LOG[lb + 256 + m]);
    float g = sigm(LOG[lb + 512 + m]);
    float bur = BU[(size_t)row * 512 + m];
    float bui = BU[(size_t)row * 512 + 256 + m];
    float r2 = fmaxf(r * r, 1e-8f);
    float A = fmaxf((r2 - 2.0f * r * cosf(th) + 1.0f) * idt2[m] / r2, 0.0f);
    float G = fmaxf((1.0f - r2) * idt[m] / r2, 0.0f);
    float4 o; o.x = A; o.y = G; o.z = bur * g; o.w = bui * g;
    *(float4*)&AG[((size_t)row * M_ + m) * 4] = o;
}

// ---------------- parallel scan: pass 1 (per-segment transform compose) ----------------
#define SEG_ 64
__global__ __launch_bounds__(256) void k_scan1(const float* __restrict__ AG,
                                               const float* __restrict__ dtc_,
                                               float* __restrict__ SEGM,  // (B*NSEG,M) float4 a,b,c,d
                                               float* __restrict__ SEGV,  // (B*NSEG,M) float4 vzr,vzi,vxr,vxi
                                               int C) {
    int m = threadIdx.x;
    int nseg = C >> 6;
    int b = blockIdx.x / nseg;
    int s = blockIdx.x - b * nseg;
    float dt = dtc_[m];
    const float4* p = (const float4*)AG + ((size_t)(b * C + s * SEG_) * M_ + m);
    float a = 1.f, bb = 0.f, c = 0.f, d = 1.f;
    float vzr = 0.f, vzi = 0.f, vxr = 0.f, vxi = 0.f;
    for (int t = 0; t < SEG_; ++t) {
        float4 v = p[(size_t)t * M_];
        float S = fmaf(dt, v.y, 1.0f);
        float e = 1.0f / fmaxf(S, 1e-6f);
        float sa = e;
        float sb = -dt * v.x * e;
        float sc = dt * e;
        float sd = fmaf(dt, sb, 1.0f);
        float na = fmaf(sa, a, sb * c), nb = fmaf(sa, bb, sb * d);
        float nc = fmaf(sc, a, sd * c), nd = fmaf(sc, bb, sd * d);
        float wz = dt * e;
        float nvzr = fmaf(sa, vzr, fmaf(sb, vxr, wz * v.z));
        float nvzi = fmaf(sa, vzi, fmaf(sb, vxi, wz * v.w));
        float nvxr = fmaf(sc, vzr, fmaf(sd, vxr, dt * wz * v.z));
        float nvxi = fmaf(sc, vzi, fmaf(sd, vxi, dt * wz * v.w));
        a = na; bb = nb; c = nc; d = nd;
        vzr = nvzr; vzi = nvzi; vxr = nvxr; vxi = nvxi;
    }
    size_t o = ((size_t)blockIdx.x * M_ + m) * 4;
    *(float4*)&SEGM[o] = make_float4(a, bb, c, d);
    *(float4*)&SEGV[o] = make_float4(vzr, vzi, vxr, vxi);
}

// ---------------- scan pass 2: sequential over segments ----------------
__global__ __launch_bounds__(256) void k_scan2(const float* __restrict__ SEGM,
                                               const float* __restrict__ SEGV,
                                               float* __restrict__ carry,  // (B*M) float4 zr,zi,xr,xi
                                               float* __restrict__ PRE,    // (B*NSEG,M) float4
                                               int C) {
    int m = threadIdx.x;
    int b = blockIdx.x;
    int nseg = C >> 6;
    float4 st = *(float4*)&carry[(size_t)(b * M_ + m) * 4];
    for (int s = 0; s < nseg; ++s) {
        size_t o = ((size_t)(b * nseg + s) * M_ + m) * 4;
        *(float4*)&PRE[o] = st;
        float4 Mm = *(const float4*)&SEGM[o];
        float4 Vv = *(const float4*)&SEGV[o];
        float nzr = fmaf(Mm.x, st.x, fmaf(Mm.y, st.z, Vv.x));
        float nzi = fmaf(Mm.x, st.y, fmaf(Mm.y, st.w, Vv.y));
        float nxr = fmaf(Mm.z, st.x, fmaf(Mm.w, st.z, Vv.z));
        float nxi = fmaf(Mm.z, st.y, fmaf(Mm.w, st.w, Vv.w));
        st = make_float4(nzr, nzi, nxr, nxi);
    }
    *(float4*)&carry[(size_t)(b * M_ + m) * 4] = st;
}

// ---------------- scan pass 3: re-apply within segment, write XS ----------------
__global__ __launch_bounds__(256) void k_scan3(const float* __restrict__ AG,
                                               const float* __restrict__ dtc_,
                                               const float* __restrict__ PRE,
                                               float* __restrict__ XS,  // (rows,512) re,im interleaved
                                               int C) {
    int m = threadIdx.x;
    int nseg = C >> 6;
    int b = blockIdx.x / nseg;
    int s = blockIdx.x - b * nseg;
    float dt = dtc_[m];
    float4 st = *(const float4*)&PRE[((size_t)blockIdx.x * M_ + m) * 4];
    float zr = st.x, zi = st.y, xr = st.z, xi = st.w;
    const float4* p = (const float4*)AG + ((size_t)(b * C + s * SEG_) * M_ + m);
    float2* q = (float2*)XS + ((size_t)(b * C + s * SEG_) * M_ + m);
    for (int t = 0; t < SEG_; ++t) {
        float4 v = p[(size_t)t * M_];
        float S = fmaf(dt, v.y, 1.0f);
        float inv = 1.0f / fmaxf(S, 1e-6f);
        zr = fmaf(dt, fmaf(-v.x, xr, v.z), zr) * inv;
        zi = fmaf(dt, fmaf(-v.x, xi, v.w), zi) * inv;
        xr = fmaf(dt, zr, xr);
        xi = fmaf(dt, zi, xi);
        q[(size_t)t * M_] = make_float2(xr, xi);
    }
}

extern "C" void kernel_launch(void* const* d_in, const int* in_sizes, int n_in,
                              void* d_out, int out_size, void* d_ws, size_t ws_size,
                              hipStream_t stream) {
    const float* inputs = (const float*)d_in[0];
    const float* Bp     = (const float*)d_in[1];
    const float* Cp     = (const float*)d_in[2];
    const float* Dv     = (const float*)d_in[3];
    const float* enc_w  = (const float*)d_in[4];
    const float* enc_b  = (const float*)d_in[5];
    const float* conv_w = (const float*)d_in[6];
    const float* conv_b = (const float*)d_in[7];
    const float* rlb    = (const float*)d_in[8];
    const float* tab    = (const float*)d_in[9];
    const float* Wr     = (const float*)d_in[10];
    const float* Wt     = (const float*)d_in[11];
    const float* dtb    = (const float*)d_in[12];
    const float* Wg     = (const float*)d_in[13];

    // pick largest chunk length C (multiple of 128) that fits ws_size
    int C = 4096;
    while (C > 128) {
        size_t need = (size_t)B_ * C * 11264 + (8ull << 20);
        if (need <= ws_size) break;
        C >>= 1;
    }

    char* ws = (char*)d_ws;
    size_t off = 0;
    auto alloc = [&](size_t bytes) -> float* {
        float* p = (float*)(ws + off);
        off = (off + bytes + 1023) & ~(size_t)1023;
        return p;
    };
    const int rows = B_ * C;
    const int nseg = C >> 6;
    float* F0   = alloc((size_t)rows * H_ * 4);
    float* F    = alloc((size_t)rows * H_ * 4);
    float* LOG  = alloc((size_t)rows * 768 * 4);   // reused as XS
    float* BU   = alloc((size_t)rows * 512 * 4);   // reused as SEGM/SEGV/PRE
    float* AG   = alloc((size_t)rows * M_ * 16);
    float* WB   = alloc(2 * 65536 * 4);
    float* WH   = alloc(3 * 65536 * 4);
    float* Chat = alloc(H_ * 512 * 4);
    float* dtc  = alloc(1024);
    float* idt  = alloc(1024);
    float* idt2 = alloc(1024);
    float* carry = alloc(B_ * M_ * 16);
    float* TAIL = alloc(B_ * 3 * H_ * 4);
    float* XS   = LOG;
    float* SEGM = BU;
    float* SEGV = SEGM + (size_t)B_ * nseg * M_ * 4;
    float* PRE  = SEGV + (size_t)B_ * nseg * M_ * 4;

    const int NC = L_ / C;
    const int tpb = C >> 7;

    k_prep<<<256, 256, 0, stream>>>(Bp, Cp, Wr, Wt, Wg, dtb, WB, WH, Chat, dtc, idt, idt2);
    k_zero<<<(B_ * M_ * 4 + 255) / 256, 256, 0, stream>>>(carry, B_ * M_ * 4);

    for (int c = 0; c < NC; ++c) {
        int t0 = c * C;
        k_gemm<1, true, false><<<dim3(2, B_ * tpb), 256, 0, stream>>>(
            inputs, enc_w, F0, enc_b, nullptr, 256, 256, C, t0);
        k_conv<<<rows, 256, 0, stream>>>(F0, TAIL, conv_w, conv_b, F, t0, C);
        k_tail<<<B_ * 3, 256, 0, stream>>>(F0, TAIL, C);
        k_gemm<0, false, false><<<dim3(6, B_ * tpb), 256, 0, stream>>>(
            F, WH, LOG, nullptr, nullptr, 256, 768, C, t0);
        k_gemm<0, true, false><<<dim3(4, B_ * tpb), 256, 0, stream>>>(
            inputs, WB, BU, nullptr, nullptr, 256, 512, C, t0);
        k_assemble<<<rows, 256, 0, stream>>>(LOG, BU, rlb, tab, idt, idt2, AG);
        k_scan1<<<B_ * nseg, 256, 0, stream>>>(AG, dtc, SEGM, SEGV, C);
        k_scan2<<<B_, 256, 0, stream>>>(SEGM, SEGV, carry, PRE, C);
        k_scan3<<<B_ * nseg, 256, 0, stream>>>(AG, dtc, PRE, XS, C);
        k_gemm<2, false, true><<<dim3(2, B_ * tpb), 256, 0, stream>>>(
            XS, Chat, (float*)d_out, Dv, inputs, 512, 256, C, t0);
    }
}

// Round 4
// 1124.613 us; speedup vs baseline: 2.1583x; 1.1850x over previous
//
#include <hip/hip_runtime.h>

#define H_ 256
#define M_ 256
#define L_ 4096
#define B_ 16
#define PI_F 3.14159265358979323846f

typedef unsigned short u16;
typedef __attribute__((ext_vector_type(8))) short short8v;   // 8 bf16 in 4 VGPRs
typedef __attribute__((ext_vector_type(4))) float floatx4;

__device__ __forceinline__ float sigm(float x) { return 1.0f / (1.0f + expf(-x)); }
__device__ __forceinline__ u16 f2bf(float f) {
    unsigned int u = __float_as_uint(f);
    unsigned int r = (u + 0x7fff + ((u >> 16) & 1)) >> 16;
    return (u16)r;
}

// ---------------- prep: pack weights (WH fp32; WBh, Chath bf16), per-m constants ----------------
__global__ __launch_bounds__(256) void k_prep(const float* __restrict__ Bp,   // (M,H,2)
                                              const float* __restrict__ Cp,   // (H,M,2)
                                              const float* __restrict__ Wr,
                                              const float* __restrict__ Wt,
                                              const float* __restrict__ Wg,
                                              const float* __restrict__ dtb,
                                              u16* __restrict__ WBh,     // (512,256) bf16: Bre rows, Bim rows
                                              float* __restrict__ WH,    // (768,256): Wr, Wt, Wg
                                              u16* __restrict__ Chath,   // (256,512) bf16: [h][2m]=Cre,[h][2m+1]=-Cim
                                              float* __restrict__ dtc, float* __restrict__ idt,
                                              float* __restrict__ idt2) {
    int tid = blockIdx.x * 256 + threadIdx.x;  // 0..65535
    if (tid < M_) {
        float d = fmaxf(sigm(dtb[tid]), 1e-6f);
        dtc[tid] = d;
        idt[tid] = 1.0f / d;
        idt2[tid] = 1.0f / (d * d);
    }
    WBh[tid]         = f2bf(Bp[2 * tid + 0]);
    WBh[65536 + tid] = f2bf(Bp[2 * tid + 1]);
    WH[tid]          = Wr[tid];
    WH[65536 + tid]  = Wt[tid];
    WH[131072 + tid] = Wg[tid];
    int h = tid >> 8, m = tid & (M_ - 1);
    Chath[h * 512 + 2 * m + 0] = f2bf(Cp[2 * tid + 0]);
    Chath[h * 512 + 2 * m + 1] = f2bf(-Cp[2 * tid + 1]);
}

__global__ __launch_bounds__(256) void k_zero(float* __restrict__ p, int n) {
    int i = blockIdx.x * 256 + threadIdx.x;
    if (i < n) p[i] = 0.0f;
}

// ---------------- fp32 -> bf16 conversion (inputs, full tensor) ----------------
__global__ __launch_bounds__(256) void k_tobf(const float* __restrict__ X, u16* __restrict__ Y) {
    size_t i = ((size_t)blockIdx.x * 256 + threadIdx.x) * 8;
    float4 a = *(const float4*)&X[i];
    float4 b = *(const float4*)&X[i + 4];
    u16 o[8] = {f2bf(a.x), f2bf(a.y), f2bf(a.z), f2bf(a.w),
                f2bf(b.x), f2bf(b.y), f2bf(b.z), f2bf(b.w)};
    *(short8v*)&Y[i] = *(short8v*)o;
}

// ---------------- generic fp32 GEMM: OUT(rows,N) = A(rows,K) @ W(N,K)^T ----------------
// 128x128 tile, 8x8 micro (split +-64), 256 threads. EPI: 0=raw, 1=silu(acc+bias)
template <int EPI, bool AGLOB>
__global__ __launch_bounds__(256) void k_gemm(const float* __restrict__ A,
                                              const float* __restrict__ W,
                                              float* __restrict__ OUT,
                                              const float* __restrict__ aux1,
                                              int K, int N, int C, int t0) {
    __shared__ float As[16][132];
    __shared__ float Bs[16][132];
    const int tid = threadIdx.x;
    const int tx = tid & 15, ty = tid >> 4;
    const int tpb = C >> 7;
    const int batch = blockIdx.y / tpb;
    const int i0 = (blockIdx.y % tpb) << 7;
    const int aRow0 = AGLOB ? (batch * L_ + t0 + i0) : (batch * C + i0);
    const int oRow0 = batch * C + i0;
    const int colBase = blockIdx.x << 7;
    const int lr = tid >> 2;
    const int lk = (tid & 3) << 2;
    float acc[8][8] = {};
    for (int k0 = 0; k0 < K; k0 += 16) {
        float4 a0 = *(const float4*)&A[(size_t)(aRow0 + lr) * K + k0 + lk];
        float4 a1 = *(const float4*)&A[(size_t)(aRow0 + 64 + lr) * K + k0 + lk];
        float4 b0 = *(const float4*)&W[(size_t)(colBase + lr) * K + k0 + lk];
        float4 b1 = *(const float4*)&W[(size_t)(colBase + 64 + lr) * K + k0 + lk];
        __syncthreads();
        As[lk + 0][lr] = a0.x; As[lk + 1][lr] = a0.y; As[lk + 2][lr] = a0.z; As[lk + 3][lr] = a0.w;
        As[lk + 0][64 + lr] = a1.x; As[lk + 1][64 + lr] = a1.y; As[lk + 2][64 + lr] = a1.z; As[lk + 3][64 + lr] = a1.w;
        Bs[lk + 0][lr] = b0.x; Bs[lk + 1][lr] = b0.y; Bs[lk + 2][lr] = b0.z; Bs[lk + 3][lr] = b0.w;
        Bs[lk + 0][64 + lr] = b1.x; Bs[lk + 1][64 + lr] = b1.y; Bs[lk + 2][64 + lr] = b1.z; Bs[lk + 3][64 + lr] = b1.w;
        __syncthreads();
#pragma unroll
        for (int kk = 0; kk < 16; ++kk) {
            float4 av0 = *(const float4*)&As[kk][ty << 2];
            float4 av1 = *(const float4*)&As[kk][64 + (ty << 2)];
            float4 bv0 = *(const float4*)&Bs[kk][tx << 2];
            float4 bv1 = *(const float4*)&Bs[kk][64 + (tx << 2)];
            float av[8] = {av0.x, av0.y, av0.z, av0.w, av1.x, av1.y, av1.z, av1.w};
            float bv[8] = {bv0.x, bv0.y, bv0.z, bv0.w, bv1.x, bv1.y, bv1.z, bv1.w};
#pragma unroll
            for (int i = 0; i < 8; ++i)
#pragma unroll
                for (int j = 0; j < 8; ++j) acc[i][j] = fmaf(av[i], bv[j], acc[i][j]);
        }
    }
#pragma unroll
    for (int ih = 0; ih < 2; ++ih)
#pragma unroll
        for (int i = 0; i < 4; ++i) {
            int orow = oRow0 + ih * 64 + (ty << 2) + i;
#pragma unroll
            for (int jh = 0; jh < 2; ++jh) {
                int col = colBase + jh * 64 + (tx << 2);
                float4 o;
                o.x = acc[ih * 4 + i][jh * 4 + 0];
                o.y = acc[ih * 4 + i][jh * 4 + 1];
                o.z = acc[ih * 4 + i][jh * 4 + 2];
                o.w = acc[ih * 4 + i][jh * 4 + 3];
                if (EPI == 1) {
                    float4 bb = *(const float4*)&aux1[col];
                    float v0 = o.x + bb.x, v1 = o.y + bb.y, v2 = o.z + bb.z, v3 = o.w + bb.w;
                    o.x = v0 * sigm(v0); o.y = v1 * sigm(v1); o.z = v2 * sigm(v2); o.w = v3 * sigm(v3);
                }
                *(float4*)&OUT[(size_t)orow * N + col] = o;
            }
        }
}

// ---------------- bf16 MFMA GEMM: OUT(rows,N) = A(rows,K) @ W(N,K)^T ----------------
// 128x128 tile, 4 waves (each 64x64 via 4x4 of 16x16x32), reg-prefetch double buffer.
// EPI 0 (bu):  A rows global (t0), OUT rows local;  out *= sigm(LOG[row*768+512+(col&255)])
// EPI 1 (proj):A rows local,       OUT rows global; out = acc + Dv[col]*X0[grow*256+col]
template <int EPI>
__global__ __launch_bounds__(256) void k_mgemm(const u16* __restrict__ A,
                                               const u16* __restrict__ W,
                                               float* __restrict__ OUT,
                                               const float* __restrict__ LOGg,
                                               const float* __restrict__ Dv,
                                               const float* __restrict__ X0,
                                               int K, int N, int C, int t0) {
    __shared__ u16 As[128][40];   // 80B row stride: 16B-aligned frags, ~2-way banks
    __shared__ u16 Bs[128][40];
    const int tid = threadIdx.x;
    const int tpb = C >> 7;
    const int batch = blockIdx.y / tpb;
    const int i0 = (blockIdx.y % tpb) << 7;
    const int colBase = blockIdx.x << 7;
    const int aRow0 = (EPI == 0) ? (batch * L_ + t0 + i0) : (batch * C + i0);
    const int oRow0 = (EPI == 0) ? (batch * C + i0) : (batch * L_ + t0 + i0);
    const int arow = tid >> 1, aseg = (tid & 1) << 4;  // 0 / 16
    const u16* pa = &A[(size_t)(aRow0 + arow) * K + aseg];
    const u16* pb = &W[(size_t)(colBase + arow) * K + aseg];
    short8v ra0 = *(const short8v*)pa, ra1 = *(const short8v*)(pa + 8);
    short8v rb0 = *(const short8v*)pb, rb1 = *(const short8v*)(pb + 8);
    const int lane = tid & 63, wv = tid >> 6;
    const int wr = wv >> 1, wc = wv & 1;
    const int fr = lane & 15, kg = lane >> 4;
    floatx4 acc[4][4];
#pragma unroll
    for (int i = 0; i < 4; ++i)
#pragma unroll
        for (int j = 0; j < 4; ++j) acc[i][j] = (floatx4){0.f, 0.f, 0.f, 0.f};
    const int KT = K >> 5;
    for (int kt = 0; kt < KT; ++kt) {
        __syncthreads();
        *(short8v*)&As[arow][aseg] = ra0; *(short8v*)&As[arow][aseg + 8] = ra1;
        *(short8v*)&Bs[arow][aseg] = rb0; *(short8v*)&Bs[arow][aseg + 8] = rb1;
        __syncthreads();
        if (kt + 1 < KT) {
            pa += 32; pb += 32;
            ra0 = *(const short8v*)pa; ra1 = *(const short8v*)(pa + 8);
            rb0 = *(const short8v*)pb; rb1 = *(const short8v*)(pb + 8);
        }
        short8v af[4], bf[4];
#pragma unroll
        for (int i = 0; i < 4; ++i) af[i] = *(short8v*)&As[wr * 64 + i * 16 + fr][kg << 3];
#pragma unroll
        for (int j = 0; j < 4; ++j) bf[j] = *(short8v*)&Bs[wc * 64 + j * 16 + fr][kg << 3];
#pragma unroll
        for (int i = 0; i < 4; ++i)
#pragma unroll
            for (int j = 0; j < 4; ++j)
                acc[i][j] = __builtin_amdgcn_mfma_f32_16x16x32_bf16(af[i], bf[j], acc[i][j], 0, 0, 0);
    }
    // epilogue: D[row=(lane>>4)*4+reg][col=lane&15] per 16x16 frag
#pragma unroll
    for (int i = 0; i < 4; ++i)
#pragma unroll
        for (int j = 0; j < 4; ++j) {
            int rbase = wr * 64 + i * 16 + (kg << 2);
            int col = colBase + wc * 64 + j * 16 + fr;
#pragma unroll
            for (int r = 0; r < 4; ++r) {
                int lrow = rbase + r;
                float v = acc[i][j][r];
                if (EPI == 0) {
                    int orow = oRow0 + lrow;
                    float g = sigm(LOGg[(size_t)orow * 768 + 512 + (col & 255)]);
                    OUT[(size_t)orow * N + col] = v * g;
                } else {
                    int grow = oRow0 + lrow;
                    float o = fmaf(Dv[col], X0[(size_t)grow * 256 + col], v);
                    OUT[(size_t)grow * 256 + col] = o;
                }
            }
        }
}

// ---------------- depthwise causal conv (K=4) + SiLU ----------------
__global__ __launch_bounds__(256) void k_conv(const float* __restrict__ F0,   // (B*C,H)
                                              const float* __restrict__ TAIL, // (B,3,H)
                                              const float* __restrict__ cw,
                                              const float* __restrict__ cb,
                                              float* __restrict__ F,
                                              int t0, int C) {
    int idx = blockIdx.x * 256 + threadIdx.x;
    int h = idx & (H_ - 1);
    int rl = idx >> 8;
    int b = rl / C;
    int dtl = rl - b * C;
    int t = t0 + dtl;
    float w0 = cw[h * 4 + 0], w1 = cw[h * 4 + 1], w2 = cw[h * 4 + 2], w3 = cw[h * 4 + 3];
    float acc = cb[h];
    acc = fmaf(F0[(size_t)rl * H_ + h], w3, acc);
#pragma unroll
    for (int kk = 1; kk <= 3; ++kk) {
        float w = (kk == 1) ? w2 : (kk == 2) ? w1 : w0;
        if (t - kk >= 0) {
            float src;
            if (dtl - kk >= 0) src = F0[(size_t)(rl - kk) * H_ + h];
            else               src = TAIL[((b * 3 + (3 + dtl - kk)) << 8) + h];
            acc = fmaf(src, w, acc);
        }
    }
    F[(size_t)rl * H_ + h] = acc * sigm(acc);
}

__global__ __launch_bounds__(256) void k_tail(const float* __restrict__ F0,
                                              float* __restrict__ TAIL, int C) {
    int b = blockIdx.x / 3, j = blockIdx.x % 3, h = threadIdx.x;
    TAIL[((b * 3 + j) << 8) + h] = F0[((size_t)(b * C + C - 3 + j) << 8) + h];
}

// ---------------- fused spectral-step inputs ----------------
__device__ __forceinline__ void step_in(const float* __restrict__ LOG,
                                        const float* __restrict__ BU,
                                        float rlbm, float tabm, float idtm, float idt2m,
                                        size_t row, int m,
                                        float& A, float& G, float& br, float& bi) {
    size_t lb = row * 768;
    float r = sigm(rlbm + LOG[lb + m]);
    float th = PI_F * tanhf(tabm + LOG[lb + 256 + m]);
    float r2 = fmaxf(r * r, 1e-8f);
    A = fmaxf((r2 - 2.0f * r * cosf(th) + 1.0f) * idt2m / r2, 0.0f);
    G = fmaxf((1.0f - r2) * idtm / r2, 0.0f);
    br = BU[row * 512 + m];
    bi = BU[row * 512 + 256 + m];
}

// ---------------- parallel scan: pass 1 (per-segment transform compose) ----------------
#define SEG_ 64
__global__ __launch_bounds__(256) void k_scan1(const float* __restrict__ LOG,
                                               const float* __restrict__ BU,
                                               const float* __restrict__ rlb,
                                               const float* __restrict__ tab,
                                               const float* __restrict__ idt,
                                               const float* __restrict__ idt2,
                                               const float* __restrict__ dtc_,
                                               float* __restrict__ SEGM,
                                               float* __restrict__ SEGV,
                                               int C) {
    int m = threadIdx.x;
    int nseg = C >> 6;
    int b = blockIdx.x / nseg;
    int s = blockIdx.x - b * nseg;
    float dt = dtc_[m];
    float rlbm = rlb[m], tabm = tab[m], idtm = idt[m], idt2m = idt2[m];
    size_t row0 = (size_t)b * C + s * SEG_;
    float a = 1.f, bb = 0.f, c = 0.f, d = 1.f;
    float vzr = 0.f, vzi = 0.f, vxr = 0.f, vxi = 0.f;
    for (int t = 0; t < SEG_; ++t) {
        float A, G, br, bi;
        step_in(LOG, BU, rlbm, tabm, idtm, idt2m, row0 + t, m, A, G, br, bi);
        float S = fmaf(dt, G, 1.0f);
        float e = 1.0f / fmaxf(S, 1e-6f);
        float sa = e;
        float sb = -dt * A * e;
        float sc = dt * e;
        float sd = fmaf(dt, sb, 1.0f);
        float na = fmaf(sa, a, sb * c), nb = fmaf(sa, bb, sb * d);
        float nc = fmaf(sc, a, sd * c), nd = fmaf(sc, bb, sd * d);
        float wz = dt * e;
        float nvzr = fmaf(sa, vzr, fmaf(sb, vxr, wz * br));
        float nvzi = fmaf(sa, vzi, fmaf(sb, vxi, wz * bi));
        float nvxr = fmaf(sc, vzr, fmaf(sd, vxr, dt * wz * br));
        float nvxi = fmaf(sc, vzi, fmaf(sd, vxi, dt * wz * bi));
        a = na; bb = nb; c = nc; d = nd;
        vzr = nvzr; vzi = nvzi; vxr = nvxr; vxi = nvxi;
    }
    size_t o = ((size_t)blockIdx.x * M_ + m) * 4;
    *(float4*)&SEGM[o] = make_float4(a, bb, c, d);
    *(float4*)&SEGV[o] = make_float4(vzr, vzi, vxr, vxi);
}

// ---------------- scan pass 2: sequential over segments ----------------
__global__ __launch_bounds__(256) void k_scan2(const float* __restrict__ SEGM,
                                               const float* __restrict__ SEGV,
                                               float* __restrict__ carry,
                                               float* __restrict__ PRE,
                                               int C) {
    int m = threadIdx.x;
    int b = blockIdx.x;
    int nseg = C >> 6;
    float4 st = *(float4*)&carry[(size_t)(b * M_ + m) * 4];
    for (int s = 0; s < nseg; ++s) {
        size_t o = ((size_t)(b * nseg + s) * M_ + m) * 4;
        *(float4*)&PRE[o] = st;
        float4 Mm = *(const float4*)&SEGM[o];
        float4 Vv = *(const float4*)&SEGV[o];
        float nzr = fmaf(Mm.x, st.x, fmaf(Mm.y, st.z, Vv.x));
        float nzi = fmaf(Mm.x, st.y, fmaf(Mm.y, st.w, Vv.y));
        float nxr = fmaf(Mm.z, st.x, fmaf(Mm.w, st.z, Vv.z));
        float nxi = fmaf(Mm.z, st.y, fmaf(Mm.w, st.w, Vv.w));
        st = make_float4(nzr, nzi, nxr, nxi);
    }
    *(float4*)&carry[(size_t)(b * M_ + m) * 4] = st;
}

// ---------------- scan pass 3: re-apply within segment, write bf16 XS ----------------
__global__ __launch_bounds__(256) void k_scan3(const float* __restrict__ LOG,
                                               const float* __restrict__ BU,
                                               const float* __restrict__ rlb,
                                               const float* __restrict__ tab,
                                               const float* __restrict__ idt,
                                               const float* __restrict__ idt2,
                                               const float* __restrict__ dtc_,
                                               const float* __restrict__ PRE,
                                               u16* __restrict__ XSh,  // (rows,512) bf16 re,im
                                               int C) {
    int m = threadIdx.x;
    int nseg = C >> 6;
    int b = blockIdx.x / nseg;
    int s = blockIdx.x - b * nseg;
    float dt = dtc_[m];
    float rlbm = rlb[m], tabm = tab[m], idtm = idt[m], idt2m = idt2[m];
    float4 st = *(const float4*)&PRE[((size_t)blockIdx.x * M_ + m) * 4];
    float zr = st.x, zi = st.y, xr = st.z, xi = st.w;
    size_t row0 = (size_t)b * C + s * SEG_;
    for (int t = 0; t < SEG_; ++t) {
        float A, G, br, bi;
        step_in(LOG, BU, rlbm, tabm, idtm, idt2m, row0 + t, m, A, G, br, bi);
        float S = fmaf(dt, G, 1.0f);
        float inv = 1.0f / fmaxf(S, 1e-6f);
        zr = fmaf(dt, fmaf(-A, xr, br), zr) * inv;
        zi = fmaf(dt, fmaf(-A, xi, bi), zi) * inv;
        xr = fmaf(dt, zr, xr);
        xi = fmaf(dt, zi, xi);
        unsigned int pk = (unsigned int)f2bf(xr) | ((unsigned int)f2bf(xi) << 16);
        *(unsigned int*)&XSh[(row0 + t) * 512 + 2 * m] = pk;
    }
}

extern "C" void kernel_launch(void* const* d_in, const int* in_sizes, int n_in,
                              void* d_out, int out_size, void* d_ws, size_t ws_size,
                              hipStream_t stream) {
    const float* inputs = (const float*)d_in[0];
    const float* Bp     = (const float*)d_in[1];
    const float* Cp     = (const float*)d_in[2];
    const float* Dv     = (const float*)d_in[3];
    const float* enc_w  = (const float*)d_in[4];
    const float* enc_b  = (const float*)d_in[5];
    const float* conv_w = (const float*)d_in[6];
    const float* conv_b = (const float*)d_in[7];
    const float* rlb    = (const float*)d_in[8];
    const float* tab    = (const float*)d_in[9];
    const float* Wr     = (const float*)d_in[10];
    const float* Wt     = (const float*)d_in[11];
    const float* dtb    = (const float*)d_in[12];
    const float* Wg     = (const float*)d_in[13];

    // pick largest chunk length C (multiple of 128) that fits ws_size
    int C = 4096;
    while (C > 128) {
        size_t need = (size_t)B_ * C * 8704 + (64ull << 20);
        if (need <= ws_size) break;
        C >>= 1;
    }

    char* ws = (char*)d_ws;
    size_t off = 0;
    auto alloc = [&](size_t bytes) -> char* {
        char* p = ws + off;
        off = (off + bytes + 1023) & ~(size_t)1023;
        return p;
    };
    const int rows = B_ * C;
    const int nseg = C >> 6;
    float* F0   = (float*)alloc((size_t)rows * H_ * 4);
    float* F    = (float*)alloc((size_t)rows * H_ * 4);
    float* LOG  = (float*)alloc((size_t)rows * 768 * 4);
    float* BU   = (float*)alloc((size_t)rows * 512 * 4);
    u16*   Xbf  = (u16*)alloc((size_t)B_ * L_ * H_ * 2);     // full input, bf16
    u16*   XSh  = (u16*)alloc((size_t)rows * 512 * 2);
    float* SEGM = (float*)alloc((size_t)B_ * nseg * M_ * 16);
    float* SEGV = (float*)alloc((size_t)B_ * nseg * M_ * 16);
    float* PRE  = (float*)alloc((size_t)B_ * nseg * M_ * 16);
    float* WH   = (float*)alloc(768 * 256 * 4);
    u16*   WBh  = (u16*)alloc(512 * 256 * 2);
    u16*   Chath= (u16*)alloc(256 * 512 * 2);
    float* dtc  = (float*)alloc(1024);
    float* idt  = (float*)alloc(1024);
    float* idt2 = (float*)alloc(1024);
    float* carry= (float*)alloc(B_ * M_ * 16);
    float* TAIL = (float*)alloc(B_ * 3 * H_ * 4);

    const int NC = L_ / C;
    const int tpb = C >> 7;

    k_prep<<<256, 256, 0, stream>>>(Bp, Cp, Wr, Wt, Wg, dtb, WBh, WH, Chath, dtc, idt, idt2);
    k_zero<<<(B_ * M_ * 4 + 255) / 256, 256, 0, stream>>>(carry, B_ * M_ * 4);
    k_tobf<<<(B_ * L_ * H_) / (256 * 8), 256, 0, stream>>>(inputs, Xbf);

    for (int c = 0; c < NC; ++c) {
        int t0 = c * C;
        k_gemm<1, true><<<dim3(2, B_ * tpb), 256, 0, stream>>>(
            inputs, enc_w, F0, enc_b, 256, 256, C, t0);
        k_conv<<<rows, 256, 0, stream>>>(F0, TAIL, conv_w, conv_b, F, t0, C);
        k_tail<<<B_ * 3, 256, 0, stream>>>(F0, TAIL, C);
        k_gemm<0, false><<<dim3(6, B_ * tpb), 256, 0, stream>>>(
            F, WH, LOG, nullptr, 256, 768, C, t0);
        k_mgemm<0><<<dim3(4, B_ * tpb), 256, 0, stream>>>(
            Xbf, WBh, BU, LOG, nullptr, nullptr, 256, 512, C, t0);
        k_scan1<<<B_ * nseg, 256, 0, stream>>>(LOG, BU, rlb, tab, idt, idt2, dtc, SEGM, SEGV, C);
        k_scan2<<<B_, 256, 0, stream>>>(SEGM, SEGV, carry, PRE, C);
        k_scan3<<<B_ * nseg, 256, 0, stream>>>(LOG, BU, rlb, tab, idt, idt2, dtc, PRE, XSh, C);
        k_mgemm<1><<<dim3(2, B_ * tpb), 256, 0, stream>>>(
            XSh, Chath, (float*)d_out, nullptr, Dv, inputs, 512, 256, C, t0);
    }
}

// Round 5
// 873.570 us; speedup vs baseline: 2.7786x; 1.2874x over previous
//
#include <hip/hip_runtime.h>

#define H_ 256
#define M_ 256
#define L_ 4096
#define B_ 16
#define PI_F 3.14159265358979323846f

typedef unsigned short u16;
typedef __attribute__((ext_vector_type(8))) short short8v;   // 8 bf16 in 4 VGPRs
typedef __attribute__((ext_vector_type(4))) float floatx4;

__device__ __forceinline__ float sigm(float x) { return 1.0f / (1.0f + expf(-x)); }
__device__ __forceinline__ u16 f2bf(float f) {
    unsigned int u = __float_as_uint(f);
    unsigned int r = (u + 0x7fff + ((u >> 16) & 1)) >> 16;
    return (u16)r;
}
__device__ __forceinline__ float bf2f(u16 h) { return __uint_as_float(((unsigned int)h) << 16); }
__device__ __forceinline__ void split2(float x, u16& h, u16& l) {
    h = f2bf(x);
    l = f2bf(x - bf2f(h));
}

// ---------------- prep: split/pack weights, per-m constants ----------------
__global__ __launch_bounds__(256) void k_prep(const float* __restrict__ Bp,   // (M,H,2)
                                              const float* __restrict__ Cp,   // (H,M,2)
                                              const float* __restrict__ enc_w,
                                              const float* __restrict__ Wr,
                                              const float* __restrict__ Wt,
                                              const float* __restrict__ Wg,
                                              const float* __restrict__ dtb,
                                              u16* __restrict__ EWhi, u16* __restrict__ EWlo,
                                              u16* __restrict__ HWhi, u16* __restrict__ HWlo, // 2 heads: r, theta
                                              u16* __restrict__ GWhi,
                                              u16* __restrict__ WBh,     // (512,256): Bre rows, Bim rows
                                              u16* __restrict__ Chath,   // (256,512): [h][2m]=Cre,[h][2m+1]=-Cim
                                              float* __restrict__ dtc, float* __restrict__ idt,
                                              float* __restrict__ idt2) {
    int tid = blockIdx.x * 256 + threadIdx.x;  // 0..65535
    if (tid < M_) {
        float d = fmaxf(sigm(dtb[tid]), 1e-6f);
        dtc[tid] = d;
        idt[tid] = 1.0f / d;
        idt2[tid] = 1.0f / (d * d);
    }
    u16 h, l;
    split2(enc_w[tid], h, l); EWhi[tid] = h; EWlo[tid] = l;
    split2(Wr[tid], h, l);    HWhi[tid] = h; HWlo[tid] = l;
    split2(Wt[tid], h, l);    HWhi[65536 + tid] = h; HWlo[65536 + tid] = l;
    GWhi[tid] = f2bf(Wg[tid]);
    WBh[tid]         = f2bf(Bp[2 * tid + 0]);
    WBh[65536 + tid] = f2bf(Bp[2 * tid + 1]);
    int hh = tid >> 8, m = tid & (M_ - 1);
    Chath[hh * 512 + 2 * m + 0] = f2bf(Cp[2 * tid + 0]);
    Chath[hh * 512 + 2 * m + 1] = f2bf(-Cp[2 * tid + 1]);
}

__global__ __launch_bounds__(256) void k_zero(float* __restrict__ p, int n) {
    int i = blockIdx.x * 256 + threadIdx.x;
    if (i < n) p[i] = 0.0f;
}

// ---------------- fp32 -> bf16 conversion (inputs, full tensor) ----------------
__global__ __launch_bounds__(256) void k_tobf(const float* __restrict__ X, u16* __restrict__ Y) {
    size_t i = ((size_t)blockIdx.x * 256 + threadIdx.x) * 8;
    float4 a = *(const float4*)&X[i];
    float4 b = *(const float4*)&X[i + 4];
    u16 o[8] = {f2bf(a.x), f2bf(a.y), f2bf(a.z), f2bf(a.w),
                f2bf(b.x), f2bf(b.y), f2bf(b.z), f2bf(b.w)};
    *(short8v*)&Y[i] = *(short8v*)o;
}

// ---------------- split-bf16 MFMA GEMM: fp32 A on the fly -> hi/lo, pre-split W ----------------
// OUT(rows, NH*256-ish) = A(rows,K) @ W[h](256,K)^T, NPROD=3: hi*hi + hi*lo + lo*hi.
// 128x128 tile per head, 4 waves. EPI: 1=enc(silu+bias->F0), 0=heads(r,theta->A,G), 2=gate(sigm->GT)
template <int NH, int NPROD, int EPI, bool AGLOB>
__global__ __launch_bounds__(256) void k_sgemm(const float* __restrict__ A,
                                               const u16* __restrict__ Whi,
                                               const u16* __restrict__ Wlo,
                                               float* __restrict__ OUT,
                                               const float* __restrict__ p0,  // bias | rlb | null
                                               const float* __restrict__ p1,  // tab
                                               const float* __restrict__ p2,  // idt
                                               const float* __restrict__ p3,  // idt2
                                               int K, int C, int t0) {
    constexpr int LOR = (NPROD == 3) ? 128 : 1;
    __shared__ u16 Ah[128][40];
    __shared__ u16 Al[LOR][40];
    __shared__ u16 Bh[NH][128][40];
    __shared__ u16 Bl[(NPROD == 3) ? NH : 1][128][40];
    const int tid = threadIdx.x;
    const int tpb = C >> 7;
    const int batch = blockIdx.y / tpb;
    const int i0 = (blockIdx.y % tpb) << 7;
    const int colBase = blockIdx.x << 7;
    const int aRow0 = AGLOB ? (batch * L_ + t0 + i0) : (batch * C + i0);
    const int oRow0 = batch * C + i0;
    const int arow = tid >> 1, aseg = (tid & 1) << 4;
    const float* pa = &A[(size_t)(aRow0 + arow) * K + aseg];
    float4 ra0 = *(const float4*)pa, ra1 = *(const float4*)(pa + 4);
    float4 ra2 = *(const float4*)(pa + 8), ra3 = *(const float4*)(pa + 12);
    const int lane = tid & 63, wv = tid >> 6;
    const int wr = wv >> 1, wc = wv & 1;
    const int fr = lane & 15, kg = lane >> 4;
    floatx4 acc[NH][4][4];
#pragma unroll
    for (int h = 0; h < NH; ++h)
#pragma unroll
        for (int i = 0; i < 4; ++i)
#pragma unroll
            for (int j = 0; j < 4; ++j) acc[h][i][j] = (floatx4){0.f, 0.f, 0.f, 0.f};
    const int KT = K >> 5;
    for (int kt = 0; kt < KT; ++kt) {
        // B regs for this step (L2-hot weights)
        short8v rbh[NH][2], rbl[(NPROD == 3) ? NH : 1][2];
#pragma unroll
        for (int h = 0; h < NH; ++h) {
            const u16* pb = &Whi[(size_t)h * 65536 + (size_t)(colBase + arow) * K + kt * 32 + aseg];
            rbh[h][0] = *(const short8v*)pb; rbh[h][1] = *(const short8v*)(pb + 8);
            if (NPROD == 3) {
                const u16* pl = &Wlo[(size_t)h * 65536 + (size_t)(colBase + arow) * K + kt * 32 + aseg];
                rbl[h][0] = *(const short8v*)pl; rbl[h][1] = *(const short8v*)(pl + 8);
            }
        }
        __syncthreads();
        {
            u16 hb[16], lb[16];
            float v[16] = {ra0.x, ra0.y, ra0.z, ra0.w, ra1.x, ra1.y, ra1.z, ra1.w,
                           ra2.x, ra2.y, ra2.z, ra2.w, ra3.x, ra3.y, ra3.z, ra3.w};
#pragma unroll
            for (int s = 0; s < 16; ++s) {
                if (NPROD == 3) split2(v[s], hb[s], lb[s]);
                else hb[s] = f2bf(v[s]);
            }
            *(short8v*)&Ah[arow][aseg] = *(short8v*)&hb[0];
            *(short8v*)&Ah[arow][aseg + 8] = *(short8v*)&hb[8];
            if (NPROD == 3) {
                *(short8v*)&Al[arow][aseg] = *(short8v*)&lb[0];
                *(short8v*)&Al[arow][aseg + 8] = *(short8v*)&lb[8];
            }
        }
#pragma unroll
        for (int h = 0; h < NH; ++h) {
            *(short8v*)&Bh[h][arow][aseg] = rbh[h][0];
            *(short8v*)&Bh[h][arow][aseg + 8] = rbh[h][1];
            if (NPROD == 3) {
                *(short8v*)&Bl[h][arow][aseg] = rbl[h][0];
                *(short8v*)&Bl[h][arow][aseg + 8] = rbl[h][1];
            }
        }
        __syncthreads();
        if (kt + 1 < KT) {
            pa += 32;
            ra0 = *(const float4*)pa; ra1 = *(const float4*)(pa + 4);
            ra2 = *(const float4*)(pa + 8); ra3 = *(const float4*)(pa + 12);
        }
        short8v afh[4], afl[4];
#pragma unroll
        for (int i = 0; i < 4; ++i) afh[i] = *(short8v*)&Ah[wr * 64 + i * 16 + fr][kg << 3];
        if (NPROD == 3) {
#pragma unroll
            for (int i = 0; i < 4; ++i) afl[i] = *(short8v*)&Al[wr * 64 + i * 16 + fr][kg << 3];
        }
#pragma unroll
        for (int h = 0; h < NH; ++h) {
            short8v bfh[4], bfl[4];
#pragma unroll
            for (int j = 0; j < 4; ++j) bfh[j] = *(short8v*)&Bh[h][wc * 64 + j * 16 + fr][kg << 3];
            if (NPROD == 3) {
#pragma unroll
                for (int j = 0; j < 4; ++j) bfl[j] = *(short8v*)&Bl[h][wc * 64 + j * 16 + fr][kg << 3];
            }
#pragma unroll
            for (int i = 0; i < 4; ++i)
#pragma unroll
                for (int j = 0; j < 4; ++j) {
                    floatx4 t = acc[h][i][j];
                    if (NPROD == 3) {
                        t = __builtin_amdgcn_mfma_f32_16x16x32_bf16(afl[i], bfh[j], t, 0, 0, 0);
                        t = __builtin_amdgcn_mfma_f32_16x16x32_bf16(afh[i], bfl[j], t, 0, 0, 0);
                    }
                    t = __builtin_amdgcn_mfma_f32_16x16x32_bf16(afh[i], bfh[j], t, 0, 0, 0);
                    acc[h][i][j] = t;
                }
        }
    }
    // epilogue: D[row=(lane>>4)*4+reg][col=lane&15]
#pragma unroll
    for (int i = 0; i < 4; ++i)
#pragma unroll
        for (int j = 0; j < 4; ++j) {
            int rbase = wr * 64 + i * 16 + (kg << 2);
            int col = colBase + wc * 64 + j * 16 + fr;
#pragma unroll
            for (int r = 0; r < 4; ++r) {
                int orow = oRow0 + rbase + r;
                if (EPI == 1) {
                    float v = acc[0][i][j][r] + p0[col];
                    OUT[(size_t)orow * 256 + col] = v * sigm(v);
                } else if (EPI == 2) {
                    OUT[(size_t)orow * 256 + col] = sigm(acc[0][i][j][r]);
                } else {
                    float rr = sigm(p0[col] + acc[0][i][j][r]);
                    float th = PI_F * tanhf(p1[col] + acc[1][i][j][r]);
                    float r2 = fmaxf(rr * rr, 1e-8f);
                    float Av = fmaxf((r2 - 2.0f * rr * cosf(th) + 1.0f) * p3[col] / r2, 0.0f);
                    float Gv = fmaxf((1.0f - r2) * p2[col] / r2, 0.0f);
                    *(float2*)&OUT[((size_t)orow * 256 + col) * 2] = make_float2(Av, Gv);
                }
            }
        }
}

// ---------------- bf16 MFMA GEMM (A already bf16): bu / proj ----------------
// EPI 0 (bu):  A rows global (t0), OUT rows local; out *= GT[orow*256+(col&255)]
// EPI 1 (proj):A rows local, OUT rows global; out = acc + Dv[col]*X0[grow*256+col]
template <int EPI>
__global__ __launch_bounds__(256) void k_mgemm(const u16* __restrict__ A,
                                               const u16* __restrict__ W,
                                               float* __restrict__ OUT,
                                               const float* __restrict__ GT,
                                               const float* __restrict__ Dv,
                                               const float* __restrict__ X0,
                                               int K, int N, int C, int t0) {
    __shared__ u16 As[128][40];
    __shared__ u16 Bs[128][40];
    const int tid = threadIdx.x;
    const int tpb = C >> 7;
    const int batch = blockIdx.y / tpb;
    const int i0 = (blockIdx.y % tpb) << 7;
    const int colBase = blockIdx.x << 7;
    const int aRow0 = (EPI == 0) ? (batch * L_ + t0 + i0) : (batch * C + i0);
    const int oRow0 = (EPI == 0) ? (batch * C + i0) : (batch * L_ + t0 + i0);
    const int arow = tid >> 1, aseg = (tid & 1) << 4;
    const u16* pa = &A[(size_t)(aRow0 + arow) * K + aseg];
    const u16* pb = &W[(size_t)(colBase + arow) * K + aseg];
    short8v ra0 = *(const short8v*)pa, ra1 = *(const short8v*)(pa + 8);
    short8v rb0 = *(const short8v*)pb, rb1 = *(const short8v*)(pb + 8);
    const int lane = tid & 63, wv = tid >> 6;
    const int wr = wv >> 1, wc = wv & 1;
    const int fr = lane & 15, kg = lane >> 4;
    floatx4 acc[4][4];
#pragma unroll
    for (int i = 0; i < 4; ++i)
#pragma unroll
        for (int j = 0; j < 4; ++j) acc[i][j] = (floatx4){0.f, 0.f, 0.f, 0.f};
    const int KT = K >> 5;
    for (int kt = 0; kt < KT; ++kt) {
        __syncthreads();
        *(short8v*)&As[arow][aseg] = ra0; *(short8v*)&As[arow][aseg + 8] = ra1;
        *(short8v*)&Bs[arow][aseg] = rb0; *(short8v*)&Bs[arow][aseg + 8] = rb1;
        __syncthreads();
        if (kt + 1 < KT) {
            pa += 32; pb += 32;
            ra0 = *(const short8v*)pa; ra1 = *(const short8v*)(pa + 8);
            rb0 = *(const short8v*)pb; rb1 = *(const short8v*)(pb + 8);
        }
        short8v af[4], bf[4];
#pragma unroll
        for (int i = 0; i < 4; ++i) af[i] = *(short8v*)&As[wr * 64 + i * 16 + fr][kg << 3];
#pragma unroll
        for (int j = 0; j < 4; ++j) bf[j] = *(short8v*)&Bs[wc * 64 + j * 16 + fr][kg << 3];
#pragma unroll
        for (int i = 0; i < 4; ++i)
#pragma unroll
            for (int j = 0; j < 4; ++j)
                acc[i][j] = __builtin_amdgcn_mfma_f32_16x16x32_bf16(af[i], bf[j], acc[i][j], 0, 0, 0);
    }
#pragma unroll
    for (int i = 0; i < 4; ++i)
#pragma unroll
        for (int j = 0; j < 4; ++j) {
            int rbase = wr * 64 + i * 16 + (kg << 2);
            int col = colBase + wc * 64 + j * 16 + fr;
#pragma unroll
            for (int r = 0; r < 4; ++r) {
                int lrow = rbase + r;
                float v = acc[i][j][r];
                if (EPI == 0) {
                    int orow = oRow0 + lrow;
                    float g = GT[(size_t)orow * 256 + (col & 255)];
                    OUT[(size_t)orow * N + col] = v * g;
                } else {
                    int grow = oRow0 + lrow;
                    OUT[(size_t)grow * 256 + col] = fmaf(Dv[col], X0[(size_t)grow * 256 + col], v);
                }
            }
        }
}

// ---------------- depthwise causal conv (K=4) + SiLU ----------------
__global__ __launch_bounds__(256) void k_conv(const float* __restrict__ F0,   // (B*C,H)
                                              const float* __restrict__ TAIL, // (B,3,H)
                                              const float* __restrict__ cw,
                                              const float* __restrict__ cb,
                                              float* __restrict__ F,
                                              int t0, int C) {
    int idx = blockIdx.x * 256 + threadIdx.x;
    int h = idx & (H_ - 1);
    int rl = idx >> 8;
    int b = rl / C;
    int dtl = rl - b * C;
    int t = t0 + dtl;
    float w0 = cw[h * 4 + 0], w1 = cw[h * 4 + 1], w2 = cw[h * 4 + 2], w3 = cw[h * 4 + 3];
    float acc = cb[h];
    acc = fmaf(F0[(size_t)rl * H_ + h], w3, acc);
#pragma unroll
    for (int kk = 1; kk <= 3; ++kk) {
        float w = (kk == 1) ? w2 : (kk == 2) ? w1 : w0;
        if (t - kk >= 0) {
            float src;
            if (dtl - kk >= 0) src = F0[(size_t)(rl - kk) * H_ + h];
            else               src = TAIL[((b * 3 + (3 + dtl - kk)) << 8) + h];
            acc = fmaf(src, w, acc);
        }
    }
    F[(size_t)rl * H_ + h] = acc * sigm(acc);
}

__global__ __launch_bounds__(256) void k_tail(const float* __restrict__ F0,
                                              float* __restrict__ TAIL, int C) {
    int b = blockIdx.x / 3, j = blockIdx.x % 3, h = threadIdx.x;
    TAIL[((b * 3 + j) << 8) + h] = F0[((size_t)(b * C + C - 3 + j) << 8) + h];
}

// ---------------- parallel scan over chunk ----------------
#define SEG_ 64
__global__ __launch_bounds__(256) void k_scan1(const float* __restrict__ AGf2,
                                               const float* __restrict__ BU,
                                               const float* __restrict__ dtc_,
                                               float* __restrict__ SEGM,
                                               float* __restrict__ SEGV,
                                               int C) {
    int m = threadIdx.x;
    int nseg = C >> 6;
    int b = blockIdx.x / nseg;
    int s = blockIdx.x - b * nseg;
    float dt = dtc_[m];
    size_t row0 = (size_t)b * C + s * SEG_;
    float a = 1.f, bb = 0.f, c = 0.f, d = 1.f;
    float vzr = 0.f, vzi = 0.f, vxr = 0.f, vxi = 0.f;
    for (int t = 0; t < SEG_; ++t) {
        size_t row = row0 + t;
        float2 ag = *(const float2*)&AGf2[(row * 256 + m) * 2];
        float br = BU[row * 512 + m];
        float bi = BU[row * 512 + 256 + m];
        float S = fmaf(dt, ag.y, 1.0f);
        float e = 1.0f / fmaxf(S, 1e-6f);
        float sa = e;
        float sb = -dt * ag.x * e;
        float sc = dt * e;
        float sd = fmaf(dt, sb, 1.0f);
        float na = fmaf(sa, a, sb * c), nb = fmaf(sa, bb, sb * d);
        float nc = fmaf(sc, a, sd * c), nd = fmaf(sc, bb, sd * d);
        float wz = dt * e;
        float nvzr = fmaf(sa, vzr, fmaf(sb, vxr, wz * br));
        float nvzi = fmaf(sa, vzi, fmaf(sb, vxi, wz * bi));
        float nvxr = fmaf(sc, vzr, fmaf(sd, vxr, dt * wz * br));
        float nvxi = fmaf(sc, vzi, fmaf(sd, vxi, dt * wz * bi));
        a = na; bb = nb; c = nc; d = nd;
        vzr = nvzr; vzi = nvzi; vxr = nvxr; vxi = nvxi;
    }
    size_t o = ((size_t)blockIdx.x * M_ + m) * 4;
    *(float4*)&SEGM[o] = make_float4(a, bb, c, d);
    *(float4*)&SEGV[o] = make_float4(vzr, vzi, vxr, vxi);
}

__global__ __launch_bounds__(256) void k_scan2(const float* __restrict__ SEGM,
                                               const float* __restrict__ SEGV,
                                               float* __restrict__ carry,
                                               float* __restrict__ PRE,
                                               int C) {
    int m = threadIdx.x;
    int b = blockIdx.x;
    int nseg = C >> 6;
    float4 st = *(float4*)&carry[(size_t)(b * M_ + m) * 4];
    for (int s = 0; s < nseg; ++s) {
        size_t o = ((size_t)(b * nseg + s) * M_ + m) * 4;
        *(float4*)&PRE[o] = st;
        float4 Mm = *(const float4*)&SEGM[o];
        float4 Vv = *(const float4*)&SEGV[o];
        float nzr = fmaf(Mm.x, st.x, fmaf(Mm.y, st.z, Vv.x));
        float nzi = fmaf(Mm.x, st.y, fmaf(Mm.y, st.w, Vv.y));
        float nxr = fmaf(Mm.z, st.x, fmaf(Mm.w, st.z, Vv.z));
        float nxi = fmaf(Mm.z, st.y, fmaf(Mm.w, st.w, Vv.w));
        st = make_float4(nzr, nzi, nxr, nxi);
    }
    *(float4*)&carry[(size_t)(b * M_ + m) * 4] = st;
}

__global__ __launch_bounds__(256) void k_scan3(const float* __restrict__ AGf2,
                                               const float* __restrict__ BU,
                                               const float* __restrict__ dtc_,
                                               const float* __restrict__ PRE,
                                               u16* __restrict__ XSh,  // (rows,512) bf16 re,im
                                               int C) {
    int m = threadIdx.x;
    int nseg = C >> 6;
    int b = blockIdx.x / nseg;
    int s = blockIdx.x - b * nseg;
    float dt = dtc_[m];
    float4 st = *(const float4*)&PRE[((size_t)blockIdx.x * M_ + m) * 4];
    float zr = st.x, zi = st.y, xr = st.z, xi = st.w;
    size_t row0 = (size_t)b * C + s * SEG_;
    for (int t = 0; t < SEG_; ++t) {
        size_t row = row0 + t;
        float2 ag = *(const float2*)&AGf2[(row * 256 + m) * 2];
        float br = BU[row * 512 + m];
        float bi = BU[row * 512 + 256 + m];
        float S = fmaf(dt, ag.y, 1.0f);
        float inv = 1.0f / fmaxf(S, 1e-6f);
        zr = fmaf(dt, fmaf(-ag.x, xr, br), zr) * inv;
        zi = fmaf(dt, fmaf(-ag.x, xi, bi), zi) * inv;
        xr = fmaf(dt, zr, xr);
        xi = fmaf(dt, zi, xi);
        unsigned int pk = (unsigned int)f2bf(xr) | ((unsigned int)f2bf(xi) << 16);
        *(unsigned int*)&XSh[row * 512 + 2 * m] = pk;
    }
}

extern "C" void kernel_launch(void* const* d_in, const int* in_sizes, int n_in,
                              void* d_out, int out_size, void* d_ws, size_t ws_size,
                              hipStream_t stream) {
    const float* inputs = (const float*)d_in[0];
    const float* Bp     = (const float*)d_in[1];
    const float* Cp     = (const float*)d_in[2];
    const float* Dv     = (const float*)d_in[3];
    const float* enc_w  = (const float*)d_in[4];
    const float* enc_b  = (const float*)d_in[5];
    const float* conv_w = (const float*)d_in[6];
    const float* conv_b = (const float*)d_in[7];
    const float* rlb    = (const float*)d_in[8];
    const float* tab    = (const float*)d_in[9];
    const float* Wr     = (const float*)d_in[10];
    const float* Wt     = (const float*)d_in[11];
    const float* dtb    = (const float*)d_in[12];
    const float* Wg     = (const float*)d_in[13];

    // pick largest chunk length C (multiple of 128) that fits ws_size
    int C = 4096;
    while (C > 128) {
        size_t need = (size_t)B_ * C * 8704 + (80ull << 20);
        if (need <= ws_size) break;
        C >>= 1;
    }

    char* ws = (char*)d_ws;
    size_t off = 0;
    auto alloc = [&](size_t bytes) -> char* {
        char* p = ws + off;
        off = (off + bytes + 1023) & ~(size_t)1023;
        return p;
    };
    const int rows = B_ * C;
    const int nseg = C >> 6;
    float* F0   = (float*)alloc((size_t)rows * 256 * 4);
    float* F    = (float*)alloc((size_t)rows * 256 * 4);
    float* AGf2 = (float*)alloc((size_t)rows * 512 * 4);
    float* GT   = (float*)alloc((size_t)rows * 256 * 4);
    float* BU   = (float*)alloc((size_t)rows * 512 * 4);
    u16*   Xbf  = (u16*)alloc((size_t)B_ * L_ * 256 * 2);
    u16*   XSh  = (u16*)alloc((size_t)rows * 512 * 2);
    float* SEGM = (float*)alloc((size_t)B_ * nseg * M_ * 16);
    float* SEGV = (float*)alloc((size_t)B_ * nseg * M_ * 16);
    float* PRE  = (float*)alloc((size_t)B_ * nseg * M_ * 16);
    u16* EWhi = (u16*)alloc(65536 * 2);
    u16* EWlo = (u16*)alloc(65536 * 2);
    u16* HWhi = (u16*)alloc(2 * 65536 * 2);
    u16* HWlo = (u16*)alloc(2 * 65536 * 2);
    u16* GWhi = (u16*)alloc(65536 * 2);
    u16* WBh  = (u16*)alloc(2 * 65536 * 2);
    u16* Chath= (u16*)alloc(2 * 65536 * 2);
    float* dtc  = (float*)alloc(1024);
    float* idt  = (float*)alloc(1024);
    float* idt2 = (float*)alloc(1024);
    float* carry= (float*)alloc(B_ * M_ * 16);
    float* TAIL = (float*)alloc(B_ * 3 * 256 * 4);

    const int NC = L_ / C;
    const int tpb = C >> 7;

    k_prep<<<256, 256, 0, stream>>>(Bp, Cp, enc_w, Wr, Wt, Wg, dtb,
                                    EWhi, EWlo, HWhi, HWlo, GWhi, WBh, Chath, dtc, idt, idt2);
    k_zero<<<(B_ * M_ * 4 + 255) / 256, 256, 0, stream>>>(carry, B_ * M_ * 4);
    k_tobf<<<(B_ * L_ * 256) / (256 * 8), 256, 0, stream>>>(inputs, Xbf);

    for (int c = 0; c < NC; ++c) {
        int t0 = c * C;
        // encoder: split-bf16, silu(x@EW^T+b) -> F0
        k_sgemm<1, 3, 1, true><<<dim3(2, B_ * tpb), 256, 0, stream>>>(
            inputs, EWhi, EWlo, F0, enc_b, nullptr, nullptr, nullptr, 256, C, t0);
        k_conv<<<rows, 256, 0, stream>>>(F0, TAIL, conv_w, conv_b, F, t0, C);
        k_tail<<<B_ * 3, 256, 0, stream>>>(F0, TAIL, C);
        // r/theta heads: split-bf16 -> A,G
        k_sgemm<2, 3, 0, false><<<dim3(2, B_ * tpb), 256, 0, stream>>>(
            F, HWhi, HWlo, AGf2, rlb, tab, idt, idt2, 256, C, t0);
        // gate head: plain bf16 -> sigm -> GT
        k_sgemm<1, 1, 2, false><<<dim3(2, B_ * tpb), 256, 0, stream>>>(
            F, GWhi, nullptr, GT, nullptr, nullptr, nullptr, nullptr, 256, C, t0);
        // bu: plain bf16 MFMA, gated by GT
        k_mgemm<0><<<dim3(4, B_ * tpb), 256, 0, stream>>>(
            Xbf, WBh, BU, GT, nullptr, nullptr, 256, 512, C, t0);
        k_scan1<<<B_ * nseg, 256, 0, stream>>>(AGf2, BU, dtc, SEGM, SEGV, C);
        k_scan2<<<B_, 256, 0, stream>>>(SEGM, SEGV, carry, PRE, C);
        k_scan3<<<B_ * nseg, 256, 0, stream>>>(AGf2, BU, dtc, PRE, XSh, C);
        // projection + D*x residual
        k_mgemm<1><<<dim3(2, B_ * tpb), 256, 0, stream>>>(
            XSh, Chath, (float*)d_out, nullptr, Dv, inputs, 512, 256, C, t0);
    }
}

// Round 7
// 725.129 us; speedup vs baseline: 3.3474x; 1.2047x over previous
//
#include <hip/hip_runtime.h>

#define H_ 256
#define M_ 256
#define L_ 4096
#define B_ 16
#define PI_F 3.14159265358979323846f

typedef unsigned short u16;
typedef __attribute__((ext_vector_type(8))) short short8v;   // 8 bf16 in 4 VGPRs
typedef __attribute__((ext_vector_type(4))) float floatx4;

__device__ __forceinline__ float sigm(float x) { return 1.0f / (1.0f + expf(-x)); }
__device__ __forceinline__ u16 f2bf(float f) {
    unsigned int u = __float_as_uint(f);
    unsigned int r = (u + 0x7fff + ((u >> 16) & 1)) >> 16;
    return (u16)r;
}
__device__ __forceinline__ float bf2f(u16 h) { return __uint_as_float(((unsigned int)h) << 16); }
__device__ __forceinline__ void split2(float x, u16& h, u16& l) {
    h = f2bf(x);
    l = f2bf(x - bf2f(h));
}

// ---------------- prep: split/pack weights, per-m constants ----------------
__global__ __launch_bounds__(256) void k_prep(const float* __restrict__ Bp,   // (M,H,2)
                                              const float* __restrict__ Cp,   // (H,M,2)
                                              const float* __restrict__ enc_w,
                                              const float* __restrict__ Wr,
                                              const float* __restrict__ Wt,
                                              const float* __restrict__ Wg,
                                              const float* __restrict__ dtb,
                                              u16* __restrict__ EWhi, u16* __restrict__ EWlo,
                                              u16* __restrict__ HWhi, u16* __restrict__ HWlo, // r, theta
                                              u16* __restrict__ GWhi,
                                              u16* __restrict__ WBh,     // (512,256): Bre rows, Bim rows
                                              u16* __restrict__ Chath,   // (256,512): [h][2m]=Cre,[h][2m+1]=-Cim
                                              float* __restrict__ dtc, float* __restrict__ idt,
                                              float* __restrict__ idt2) {
    int tid = blockIdx.x * 256 + threadIdx.x;  // 0..65535
    if (tid < M_) {
        float d = fmaxf(sigm(dtb[tid]), 1e-6f);
        dtc[tid] = d;
        idt[tid] = 1.0f / d;
        idt2[tid] = 1.0f / (d * d);
    }
    u16 h, l;
    split2(enc_w[tid], h, l); EWhi[tid] = h; EWlo[tid] = l;
    split2(Wr[tid], h, l);    HWhi[tid] = h; HWlo[tid] = l;
    split2(Wt[tid], h, l);    HWhi[65536 + tid] = h; HWlo[65536 + tid] = l;
    GWhi[tid] = f2bf(Wg[tid]);
    WBh[tid]         = f2bf(Bp[2 * tid + 0]);
    WBh[65536 + tid] = f2bf(Bp[2 * tid + 1]);
    int hh = tid >> 8, m = tid & (M_ - 1);
    Chath[hh * 512 + 2 * m + 0] = f2bf(Cp[2 * tid + 0]);
    Chath[hh * 512 + 2 * m + 1] = f2bf(-Cp[2 * tid + 1]);
}

__global__ __launch_bounds__(256) void k_zero(float* __restrict__ p, int n) {
    int i = blockIdx.x * 256 + threadIdx.x;
    if (i < n) p[i] = 0.0f;
}

// ---------------- split-bf16 MFMA GEMM over fp32 A ----------------
// OUT = A(rows,K) @ W[h](256,K)^T per head. NPROD=3: hi*hi+hi*lo+lo*hi; NPROD=1: hi*hi.
// EPI: 1=enc silu+bias (f32 OUT) | 0=heads r,theta -> (A,G) float2 | 2=gate sigm -> bf16
//      3=bu (NH=2) -> bf16 planes gated by g16
template <int NH, int NPROD, int EPI, bool AGLOB>
__global__ __launch_bounds__(256) void k_sgemm(const float* __restrict__ A,
                                               const u16* __restrict__ Whi,
                                               const u16* __restrict__ Wlo,
                                               void* __restrict__ OUTv,
                                               const u16* __restrict__ g16,
                                               const float* __restrict__ p0,  // bias | rlb
                                               const float* __restrict__ p1,  // tab
                                               const float* __restrict__ p2,  // idt
                                               const float* __restrict__ p3,  // idt2
                                               int K, int C, int t0) {
    constexpr int LOR = (NPROD == 3) ? 128 : 1;
    constexpr int NBL = (NPROD == 3) ? NH : 1;
    __shared__ u16 Ah[128][40];
    __shared__ u16 Al[LOR][40];
    __shared__ u16 Bh[NH][128][40];
    __shared__ u16 Bl[NBL][LOR][40];
    const int tid = threadIdx.x;
    const int tpb = C >> 7;
    const int batch = blockIdx.y / tpb;
    const int i0 = (blockIdx.y % tpb) << 7;
    const int colBase = blockIdx.x << 7;
    const int aRow0 = AGLOB ? (batch * L_ + t0 + i0) : (batch * C + i0);
    const int oRow0 = batch * C + i0;
    const int arow = tid >> 1, aseg = (tid & 1) << 4;
    const float* pa = &A[(size_t)(aRow0 + arow) * K + aseg];
    float4 ra0 = *(const float4*)pa, ra1 = *(const float4*)(pa + 4);
    float4 ra2 = *(const float4*)(pa + 8), ra3 = *(const float4*)(pa + 12);
    const int lane = tid & 63, wv = tid >> 6;
    const int wr = wv >> 1, wc = wv & 1;
    const int fr = lane & 15, kg = lane >> 4;
    floatx4 acc[NH][4][4];
#pragma unroll
    for (int h = 0; h < NH; ++h)
#pragma unroll
        for (int i = 0; i < 4; ++i)
#pragma unroll
            for (int j = 0; j < 4; ++j) acc[h][i][j] = (floatx4){0.f, 0.f, 0.f, 0.f};
    const int KT = K >> 5;
    for (int kt = 0; kt < KT; ++kt) {
        short8v rbh[NH][2], rbl[NBL][2];
#pragma unroll
        for (int h = 0; h < NH; ++h) {
            const u16* pb = &Whi[(size_t)h * 65536 + (size_t)(colBase + arow) * K + kt * 32 + aseg];
            rbh[h][0] = *(const short8v*)pb; rbh[h][1] = *(const short8v*)(pb + 8);
            if (NPROD == 3) {
                const u16* pl = &Wlo[(size_t)h * 65536 + (size_t)(colBase + arow) * K + kt * 32 + aseg];
                rbl[h][0] = *(const short8v*)pl; rbl[h][1] = *(const short8v*)(pl + 8);
            }
        }
        __syncthreads();
        {
            u16 hb[16], lb[16];
            float v[16] = {ra0.x, ra0.y, ra0.z, ra0.w, ra1.x, ra1.y, ra1.z, ra1.w,
                           ra2.x, ra2.y, ra2.z, ra2.w, ra3.x, ra3.y, ra3.z, ra3.w};
#pragma unroll
            for (int s = 0; s < 16; ++s) {
                if (NPROD == 3) split2(v[s], hb[s], lb[s]);
                else hb[s] = f2bf(v[s]);
            }
            *(short8v*)&Ah[arow][aseg] = *(short8v*)&hb[0];
            *(short8v*)&Ah[arow][aseg + 8] = *(short8v*)&hb[8];
            if (NPROD == 3) {
                *(short8v*)&Al[arow][aseg] = *(short8v*)&lb[0];
                *(short8v*)&Al[arow][aseg + 8] = *(short8v*)&lb[8];
            }
        }
#pragma unroll
        for (int h = 0; h < NH; ++h) {
            *(short8v*)&Bh[h][arow][aseg] = rbh[h][0];
            *(short8v*)&Bh[h][arow][aseg + 8] = rbh[h][1];
            if (NPROD == 3) {
                *(short8v*)&Bl[h][arow][aseg] = rbl[h][0];
                *(short8v*)&Bl[h][arow][aseg + 8] = rbl[h][1];
            }
        }
        __syncthreads();
        if (kt + 1 < KT) {
            pa += 32;
            ra0 = *(const float4*)pa; ra1 = *(const float4*)(pa + 4);
            ra2 = *(const float4*)(pa + 8); ra3 = *(const float4*)(pa + 12);
        }
        short8v afh[4], afl[4];
#pragma unroll
        for (int i = 0; i < 4; ++i) afh[i] = *(short8v*)&Ah[wr * 64 + i * 16 + fr][kg << 3];
        if (NPROD == 3) {
#pragma unroll
            for (int i = 0; i < 4; ++i) afl[i] = *(short8v*)&Al[wr * 64 + i * 16 + fr][kg << 3];
        }
#pragma unroll
        for (int h = 0; h < NH; ++h) {
            short8v bfh[4], bfl[4];
#pragma unroll
            for (int j = 0; j < 4; ++j) bfh[j] = *(short8v*)&Bh[h][wc * 64 + j * 16 + fr][kg << 3];
            if (NPROD == 3) {
#pragma unroll
                for (int j = 0; j < 4; ++j) bfl[j] = *(short8v*)&Bl[h][wc * 64 + j * 16 + fr][kg << 3];
            }
#pragma unroll
            for (int i = 0; i < 4; ++i)
#pragma unroll
                for (int j = 0; j < 4; ++j) {
                    floatx4 t = acc[h][i][j];
                    if (NPROD == 3) {
                        t = __builtin_amdgcn_mfma_f32_16x16x32_bf16(afl[i], bfh[j], t, 0, 0, 0);
                        t = __builtin_amdgcn_mfma_f32_16x16x32_bf16(afh[i], bfl[j], t, 0, 0, 0);
                    }
                    t = __builtin_amdgcn_mfma_f32_16x16x32_bf16(afh[i], bfh[j], t, 0, 0, 0);
                    acc[h][i][j] = t;
                }
        }
    }
    // epilogue: D[row=(lane>>4)*4+reg][col=lane&15]
#pragma unroll
    for (int i = 0; i < 4; ++i)
#pragma unroll
        for (int j = 0; j < 4; ++j) {
            int rbase = wr * 64 + i * 16 + (kg << 2);
            int col = colBase + wc * 64 + j * 16 + fr;
#pragma unroll
            for (int r = 0; r < 4; ++r) {
                int orow = oRow0 + rbase + r;
                if (EPI == 1) {
                    float v = acc[0][i][j][r] + p0[col];
                    ((float*)OUTv)[(size_t)orow * 256 + col] = v * sigm(v);
                } else if (EPI == 2) {
                    ((u16*)OUTv)[(size_t)orow * 256 + col] = f2bf(sigm(acc[0][i][j][r]));
                } else if (EPI == 0) {
                    float rr = sigm(p0[col] + acc[0][i][j][r]);
                    float th = PI_F * tanhf(p1[col] + acc[1][i][j][r]);
                    float r2 = fmaxf(rr * rr, 1e-8f);
                    float Av = fmaxf((r2 - 2.0f * rr * cosf(th) + 1.0f) * p3[col] / r2, 0.0f);
                    float Gv = fmaxf((1.0f - r2) * p2[col] / r2, 0.0f);
                    *(float2*)&((float*)OUTv)[((size_t)orow * 256 + col) * 2] = make_float2(Av, Gv);
                } else {  // EPI==3: bu, NH=2 planes, gated
                    float g = bf2f(g16[(size_t)orow * 256 + col]);
#pragma unroll
                    for (int h = 0; h < NH; ++h)
                        ((u16*)OUTv)[(size_t)orow * 512 + h * 256 + col] = f2bf(acc[h][i][j][r] * g);
                }
            }
        }
}

// ---------------- depthwise causal conv (K=4) + SiLU ----------------
__global__ __launch_bounds__(256) void k_conv(const float* __restrict__ F0,   // (B*C,H)
                                              const float* __restrict__ TAIL, // (B,3,H)
                                              const float* __restrict__ cw,
                                              const float* __restrict__ cb,
                                              float* __restrict__ F,
                                              int t0, int C) {
    int idx = blockIdx.x * 256 + threadIdx.x;
    int h = idx & (H_ - 1);
    int rl = idx >> 8;
    int b = rl / C;
    int dtl = rl - b * C;
    int t = t0 + dtl;
    float w0 = cw[h * 4 + 0], w1 = cw[h * 4 + 1], w2 = cw[h * 4 + 2], w3 = cw[h * 4 + 3];
    float acc = cb[h];
    acc = fmaf(F0[(size_t)rl * H_ + h], w3, acc);
#pragma unroll
    for (int kk = 1; kk <= 3; ++kk) {
        float w = (kk == 1) ? w2 : (kk == 2) ? w1 : w0;
        if (t - kk >= 0) {
            float src;
            if (dtl - kk >= 0) src = F0[(size_t)(rl - kk) * H_ + h];
            else               src = TAIL[((b * 3 + (3 + dtl - kk)) << 8) + h];
            acc = fmaf(src, w, acc);
        }
    }
    F[(size_t)rl * H_ + h] = acc * sigm(acc);
}

__global__ __launch_bounds__(256) void k_tail(const float* __restrict__ F0,
                                              float* __restrict__ TAIL, int C) {
    int b = blockIdx.x / 3, j = blockIdx.x % 3, h = threadIdx.x;
    TAIL[((b * 3 + j) << 8) + h] = F0[((size_t)(b * C + C - 3 + j) << 8) + h];
}

// ---------------- parallel scan pass 1 (per-segment transform compose) ----------------
#define SEG_ 64
__global__ __launch_bounds__(256) void k_scan1(const float* __restrict__ AGf2,
                                               const u16* __restrict__ BUh,
                                               const float* __restrict__ dtc_,
                                               float* __restrict__ SEGM,
                                               float* __restrict__ SEGV,
                                               int C) {
    int m = threadIdx.x;
    int nseg = C >> 6;
    int b = blockIdx.x / nseg;
    int s = blockIdx.x - b * nseg;
    float dt = dtc_[m];
    size_t row0 = (size_t)b * C + s * SEG_;
    float a = 1.f, bb = 0.f, c = 0.f, d = 1.f;
    float vzr = 0.f, vzi = 0.f, vxr = 0.f, vxi = 0.f;
    for (int t = 0; t < SEG_; ++t) {
        size_t row = row0 + t;
        float2 ag = *(const float2*)&AGf2[(row * 256 + m) * 2];
        float br = bf2f(BUh[row * 512 + m]);
        float bi = bf2f(BUh[row * 512 + 256 + m]);
        float S = fmaf(dt, ag.y, 1.0f);
        float e = 1.0f / fmaxf(S, 1e-6f);
        float sa = e;
        float sb = -dt * ag.x * e;
        float sc = dt * e;
        float sd = fmaf(dt, sb, 1.0f);
        float na = fmaf(sa, a, sb * c), nb = fmaf(sa, bb, sb * d);
        float nc = fmaf(sc, a, sd * c), nd = fmaf(sc, bb, sd * d);
        float wz = dt * e;
        float nvzr = fmaf(sa, vzr, fmaf(sb, vxr, wz * br));
        float nvzi = fmaf(sa, vzi, fmaf(sb, vxi, wz * bi));
        float nvxr = fmaf(sc, vzr, fmaf(sd, vxr, dt * wz * br));
        float nvxi = fmaf(sc, vzi, fmaf(sd, vxi, dt * wz * bi));
        a = na; bb = nb; c = nc; d = nd;
        vzr = nvzr; vzi = nvzi; vxr = nvxr; vxi = nvxi;
    }
    size_t o = ((size_t)blockIdx.x * M_ + m) * 4;
    *(float4*)&SEGM[o] = make_float4(a, bb, c, d);
    *(float4*)&SEGV[o] = make_float4(vzr, vzi, vxr, vxi);
}

// ---------------- scan pass 2: sequential over segments ----------------
__global__ __launch_bounds__(256) void k_scan2(const float* __restrict__ SEGM,
                                               const float* __restrict__ SEGV,
                                               float* __restrict__ carry,
                                               float* __restrict__ PRE,
                                               int C) {
    int m = threadIdx.x;
    int b = blockIdx.x;
    int nseg = C >> 6;
    float4 st = *(float4*)&carry[(size_t)(b * M_ + m) * 4];
    for (int s = 0; s < nseg; ++s) {
        size_t o = ((size_t)(b * nseg + s) * M_ + m) * 4;
        *(float4*)&PRE[o] = st;
        float4 Mm = *(const float4*)&SEGM[o];
        float4 Vv = *(const float4*)&SEGV[o];
        float nzr = fmaf(Mm.x, st.x, fmaf(Mm.y, st.z, Vv.x));
        float nzi = fmaf(Mm.x, st.y, fmaf(Mm.y, st.w, Vv.y));
        float nxr = fmaf(Mm.z, st.x, fmaf(Mm.w, st.z, Vv.z));
        float nxi = fmaf(Mm.z, st.y, fmaf(Mm.w, st.w, Vv.w));
        st = make_float4(nzr, nzi, nxr, nxi);
    }
    *(float4*)&carry[(size_t)(b * M_ + m) * 4] = st;
}

// ---------------- scan pass 3 fused with projection GEMM + D*x residual ----------------
__global__ __launch_bounds__(256) void k_scan3p(const float* __restrict__ AGf2,
                                                const u16* __restrict__ BUh,
                                                const float* __restrict__ dtc_,
                                                const float* __restrict__ PRE,
                                                const u16* __restrict__ Chath,  // (256,512)
                                                const float* __restrict__ Dv,
                                                const float* __restrict__ X0,   // inputs (global rows)
                                                float* __restrict__ OUT,        // (global rows)
                                                int t0, int C) {
    __shared__ u16 XT[32][520];   // 32 time-rows x 512 (re,im interleaved), pad->2-way banks
    __shared__ u16 Bs[256][40];   // Chat k-chunk: 256 outcols x 32 k
    const int tid = threadIdx.x;
    const int m = tid;
    const int nseg = C >> 6;
    const int b = blockIdx.x / nseg;
    const int s = blockIdx.x - b * nseg;
    const float dt = dtc_[m];
    float4 st = *(const float4*)&PRE[((size_t)blockIdx.x * M_ + m) * 4];
    float zr = st.x, zi = st.y, xr = st.z, xi = st.w;
    const size_t row0 = (size_t)b * C + s * SEG_;
    const int grow0 = b * L_ + t0 + s * SEG_;
    const int lane = tid & 63, wc = tid >> 6;
    const int fr = lane & 15, kg = lane >> 4;
#pragma unroll
    for (int half = 0; half < 2; ++half) {
        // ---- scan 32 steps, stash bf16 (xr,xi) in LDS ----
        for (int t = 0; t < 32; ++t) {
            size_t row = row0 + half * 32 + t;
            float2 ag = *(const float2*)&AGf2[(row * 256 + m) * 2];
            float br = bf2f(BUh[row * 512 + m]);
            float bi = bf2f(BUh[row * 512 + 256 + m]);
            float S = fmaf(dt, ag.y, 1.0f);
            float inv = 1.0f / fmaxf(S, 1e-6f);
            zr = fmaf(dt, fmaf(-ag.x, xr, br), zr) * inv;
            zi = fmaf(dt, fmaf(-ag.x, xi, bi), zi) * inv;
            xr = fmaf(dt, zr, xr);
            xi = fmaf(dt, zi, xi);
            unsigned int pk = (unsigned int)f2bf(xr) | ((unsigned int)f2bf(xi) << 16);
            *(unsigned int*)&XT[t][2 * m] = pk;
        }
        __syncthreads();
        // ---- projection: out(32 x 256) = XT(32 x 512) @ Chat^T ----
        floatx4 pacc[2][4];
#pragma unroll
        for (int i = 0; i < 2; ++i)
#pragma unroll
            for (int j = 0; j < 4; ++j) pacc[i][j] = (floatx4){0.f, 0.f, 0.f, 0.f};
        for (int kc = 0; kc < 16; ++kc) {
            const u16* pc = &Chath[(size_t)tid * 512 + kc * 32];
            short8v c0 = *(const short8v*)pc;
            short8v c1 = *(const short8v*)(pc + 8);
            short8v c2 = *(const short8v*)(pc + 16);
            short8v c3 = *(const short8v*)(pc + 24);
            *(short8v*)&Bs[tid][0]  = c0;
            *(short8v*)&Bs[tid][8]  = c1;
            *(short8v*)&Bs[tid][16] = c2;
            *(short8v*)&Bs[tid][24] = c3;
            __syncthreads();
            short8v af[2], bf[4];
#pragma unroll
            for (int i = 0; i < 2; ++i) af[i] = *(short8v*)&XT[i * 16 + fr][kc * 32 + (kg << 3)];
#pragma unroll
            for (int j = 0; j < 4; ++j) bf[j] = *(short8v*)&Bs[wc * 64 + j * 16 + fr][kg << 3];
#pragma unroll
            for (int i = 0; i < 2; ++i)
#pragma unroll
                for (int j = 0; j < 4; ++j)
                    pacc[i][j] = __builtin_amdgcn_mfma_f32_16x16x32_bf16(af[i], bf[j], pacc[i][j], 0, 0, 0);
            __syncthreads();
        }
        // ---- epilogue: OUT[grow][col] = pacc + Dv[col]*X0[grow][col] ----
#pragma unroll
        for (int i = 0; i < 2; ++i)
#pragma unroll
            for (int j = 0; j < 4; ++j) {
                int col = wc * 64 + j * 16 + fr;
#pragma unroll
                for (int r = 0; r < 4; ++r) {
                    int grow = grow0 + half * 32 + i * 16 + (kg << 2) + r;
                    OUT[(size_t)grow * 256 + col] =
                        fmaf(Dv[col], X0[(size_t)grow * 256 + col], pacc[i][j][r]);
                }
            }
        __syncthreads();  // XT reused by next half
    }
}

extern "C" void kernel_launch(void* const* d_in, const int* in_sizes, int n_in,
                              void* d_out, int out_size, void* d_ws, size_t ws_size,
                              hipStream_t stream) {
    const float* inputs = (const float*)d_in[0];
    const float* Bp     = (const float*)d_in[1];
    const float* Cp     = (const float*)d_in[2];
    const float* Dv     = (const float*)d_in[3];
    const float* enc_w  = (const float*)d_in[4];
    const float* enc_b  = (const float*)d_in[5];
    const float* conv_w = (const float*)d_in[6];
    const float* conv_b = (const float*)d_in[7];
    const float* rlb    = (const float*)d_in[8];
    const float* tab    = (const float*)d_in[9];
    const float* Wr     = (const float*)d_in[10];
    const float* Wt     = (const float*)d_in[11];
    const float* dtb    = (const float*)d_in[12];
    const float* Wg     = (const float*)d_in[13];

    // pick largest chunk length C (multiple of 128) that fits ws_size
    int C = 4096;
    while (C > 128) {
        size_t need = (size_t)B_ * C * 5632 + (48ull << 20);
        if (need <= ws_size) break;
        C >>= 1;
    }

    char* ws = (char*)d_ws;
    size_t off = 0;
    auto alloc = [&](size_t bytes) -> char* {
        char* p = ws + off;
        off = (off + bytes + 1023) & ~(size_t)1023;
        return p;
    };
    const int rows = B_ * C;
    const int nseg = C >> 6;
    float* F0   = (float*)alloc((size_t)rows * 256 * 4);
    float* F    = (float*)alloc((size_t)rows * 256 * 4);
    float* AGf2 = (float*)alloc((size_t)rows * 512 * 4);
    u16*   GTh  = (u16*)alloc((size_t)rows * 256 * 2);
    u16*   BUh  = (u16*)alloc((size_t)rows * 512 * 2);
    float* SEGM = (float*)alloc((size_t)B_ * nseg * M_ * 16);
    float* SEGV = (float*)alloc((size_t)B_ * nseg * M_ * 16);
    float* PRE  = (float*)alloc((size_t)B_ * nseg * M_ * 16);
    u16* EWhi = (u16*)alloc(65536 * 2);
    u16* EWlo = (u16*)alloc(65536 * 2);
    u16* HWhi = (u16*)alloc(2 * 65536 * 2);
    u16* HWlo = (u16*)alloc(2 * 65536 * 2);
    u16* GWhi = (u16*)alloc(65536 * 2);
    u16* WBh  = (u16*)alloc(2 * 65536 * 2);
    u16* Chath= (u16*)alloc(2 * 65536 * 2);
    float* dtc  = (float*)alloc(1024);
    float* idt  = (float*)alloc(1024);
    float* idt2 = (float*)alloc(1024);
    float* carry= (float*)alloc(B_ * M_ * 16);
    float* TAIL = (float*)alloc(B_ * 3 * 256 * 4);

    const int NC = L_ / C;
    const int tpb = C >> 7;

    k_prep<<<256, 256, 0, stream>>>(Bp, Cp, enc_w, Wr, Wt, Wg, dtb,
                                    EWhi, EWlo, HWhi, HWlo, GWhi, WBh, Chath, dtc, idt, idt2);
    k_zero<<<(B_ * M_ * 4 + 255) / 256, 256, 0, stream>>>(carry, B_ * M_ * 4);

    for (int c = 0; c < NC; ++c) {
        int t0 = c * C;
        // encoder: split-bf16, silu(x@EW^T+b) -> F0
        k_sgemm<1, 3, 1, true><<<dim3(2, B_ * tpb), 256, 0, stream>>>(
            inputs, EWhi, EWlo, F0, nullptr, enc_b, nullptr, nullptr, nullptr, 256, C, t0);
        k_conv<<<rows, 256, 0, stream>>>(F0, TAIL, conv_w, conv_b, F, t0, C);
        k_tail<<<B_ * 3, 256, 0, stream>>>(F0, TAIL, C);
        // r/theta heads: split-bf16 -> (A,G) float2
        k_sgemm<2, 3, 0, false><<<dim3(2, B_ * tpb), 256, 0, stream>>>(
            F, HWhi, HWlo, AGf2, nullptr, rlb, tab, idt, idt2, 256, C, t0);
        // gate head: plain bf16 -> sigm -> bf16 GTh
        k_sgemm<1, 1, 2, false><<<dim3(2, B_ * tpb), 256, 0, stream>>>(
            F, GWhi, nullptr, GTh, nullptr, nullptr, nullptr, nullptr, nullptr, 256, C, t0);
        // bu: two heads (re,im) from fp32 inputs, gated -> bf16 BUh
        k_sgemm<2, 1, 3, true><<<dim3(2, B_ * tpb), 256, 0, stream>>>(
            inputs, WBh, nullptr, BUh, GTh, nullptr, nullptr, nullptr, nullptr, 256, C, t0);
        k_scan1<<<B_ * nseg, 256, 0, stream>>>(AGf2, BUh, dtc, SEGM, SEGV, C);
        k_scan2<<<B_, 256, 0, stream>>>(SEGM, SEGV, carry, PRE, C);
        // scan pass 3 fused with projection + residual
        k_scan3p<<<B_ * nseg, 256, 0, stream>>>(AGf2, BUh, dtc, PRE, Chath, Dv, inputs,
                                                (float*)d_out, t0, C);
    }
}